// Round 2
// baseline (640.445 us; speedup 1.0000x reference)
//
#include <hip/hip_runtime.h>
#include <hip/hip_fp16.h>
#include <math.h>

// ---------------------------------------------------------------------------
// NetGlobGATFix. R18: kill split-K round-trip + fix CNN occupancy.
//   - gemm_mr(SPLIT=4)+reduce_ep (184 MB P traffic, 8 dispatches) replaced by
//     gemm_sw<JT>: 1 wave per 16 rows, JT=M/16 col-tiles in registers,
//     A read exactly once, B L2-resident, fused selu/mask epilogue. 4 dispatches.
//   - conv3x3_pad: 1 output row/thread, grid.x 4->16 (96 -> 384+ blocks for
//     the heavy convs; was 1.5 blocks/CU on a 256-CU chip).
//   - P buffer dropped from workspace. Everything else identical to R17 (609us).
// ---------------------------------------------------------------------------

#define DEVFN static __device__ __forceinline__

typedef __attribute__((ext_vector_type(8))) _Float16 half8;
typedef __attribute__((ext_vector_type(4))) float f32x4;

DEVFN float selu_f(float v) {
    const float scale = 1.0507009873554805f;
    const float alpha = 1.6732632423543772f;
    return v > 0.f ? scale * v : scale * alpha * (expf(v) - 1.f);
}

DEVFN float lrelu02(float v) { return v > 0.f ? v : 0.2f * v; }

// ---------------- CNN (padded 66x66 layout) ----------------
#define PST 66
#define PSZ (66 * 66)

__global__ void pad_input(const float* __restrict__ cf, float* __restrict__ out) {
    int t = blockIdx.x * blockDim.x + threadIdx.x;
    if (t >= 4 * 4096) return;
    int c = t >> 12, pix = t & 4095;
    int y = pix >> 6, x = pix & 63;
    out[c * PSZ + (y + 1) * PST + (x + 1)] = cf[t];
}

// 1 output row per thread; grid = (16, CO). 4x the block parallelism of the
// old 4-row/thread version (conv<64> was 96 blocks on 256 CUs).
template <int CIN>
__global__ __launch_bounds__(256) void conv3x3_pad(const float* __restrict__ in,
                                                   const float* __restrict__ w,
                                                   const float* __restrict__ b,
                                                   float* __restrict__ out) {
    int x  = threadIdx.x & 63;
    int yg = threadIdx.x >> 6;
    int y  = blockIdx.x * 4 + yg;          // 0..63
    int co = blockIdx.y;
    float acc = b[co];
    const float* wp = w + (size_t)co * CIN * 9;
#pragma unroll 4
    for (int ci = 0; ci < CIN; ++ci) {
        const float* ip = in + ci * PSZ + y * PST + x;
        const float* wr = wp + ci * 9;
        acc += wr[0] * ip[0]           + wr[1] * ip[1]           + wr[2] * ip[2]
             + wr[3] * ip[PST]         + wr[4] * ip[PST + 1]     + wr[5] * ip[PST + 2]
             + wr[6] * ip[2 * PST]     + wr[7] * ip[2 * PST + 1] + wr[8] * ip[2 * PST + 2];
    }
    out[(size_t)co * PSZ + (y + 1) * PST + (x + 1)] = selu_f(acc);
}

__global__ void avgpool_c(const float* __restrict__ in, float* __restrict__ gfeat) {
    int c = blockIdx.x;            // 24 blocks
    int t = threadIdx.x;           // 256 threads
    float s = 0.f;
    for (int i = t; i < 4096; i += 256) {
        int y = i >> 6, x = i & 63;
        s += in[c * PSZ + (y + 1) * PST + (x + 1)];
    }
#pragma unroll
    for (int off = 32; off >= 1; off >>= 1) s += __shfl_xor(s, off);
    __shared__ float red[4];
    int wave = t >> 6, lane = t & 63;
    if (lane == 0) red[wave] = s;
    __syncthreads();
    if (t == 0) gfeat[c] = (red[0] + red[1] + red[2] + red[3]) * (1.f / 4096.f);
}

// ---------------- node feature init (padded to 48 ch, fp16) + masks ---------
__global__ void build_h0(const float* __restrict__ x, const float* __restrict__ gfeat,
                         __half* __restrict__ h0f, unsigned* __restrict__ masks, int N) {
    int n = blockIdx.x * blockDim.x + threadIdx.x;
    if (n >= N) return;
    float x0 = x[n * 10 + 0], x1 = x[n * 10 + 1];
    unsigned mk = (x0 == 1.f ? 1u : 0u) | (x0 == 0.f ? 2u : 0u) |
                  (x1 == 0.f ? 4u : 0u) | (x1 == 1.f ? 8u : 0u);
    masks[n] = mk;
    __half* hq = h0f + (size_t)n * 48;
#pragma unroll
    for (int j = 0; j < 48; ++j) {
        float v = (j < 24) ? gfeat[j] : (j < 34 ? x[n * 10 + (j - 24)] : 0.f);
        hq[j] = __float2half(v);
    }
}

// ---------------- CSR build (parallel scan) ----------------
__global__ void count_dst(const int* __restrict__ ei, int* __restrict__ cnt, int E, int N) {
    int t = blockIdx.x * blockDim.x + threadIdx.x;
    if (t >= E + N) return;
    int dst = (t < E) ? ei[E + t] : (t - E);
    atomicAdd(&cnt[dst], 1);
}

__global__ void scan_blocks(const int* __restrict__ cnt, int* __restrict__ pref,
                            int* __restrict__ bsums, int n) {
    __shared__ int sdata[256];
    int i = blockIdx.x * 256 + threadIdx.x;
    int v = (i < n) ? cnt[i] : 0;
    sdata[threadIdx.x] = v;
    __syncthreads();
    for (int off = 1; off < 256; off <<= 1) {
        int tmp = (threadIdx.x >= off) ? sdata[threadIdx.x - off] : 0;
        __syncthreads();
        sdata[threadIdx.x] += tmp;
        __syncthreads();
    }
    if (i < n) pref[i] = sdata[threadIdx.x] - v;
    if (threadIdx.x == 255) bsums[blockIdx.x] = sdata[255];
}

__global__ void scan_sums(int* __restrict__ bsums, int nb) {
    int tid = threadIdx.x;                 // 64
    int orig = (tid < nb) ? bsums[tid] : 0;
    int v = orig;
#pragma unroll
    for (int off = 1; off < 64; off <<= 1) {
        int u = __shfl_up(v, off);
        if (tid >= off) v += u;
    }
    if (tid < nb) bsums[tid] = v - orig;
}

__global__ void scan_apply(const int* __restrict__ pref, const int* __restrict__ bsums,
                           int* __restrict__ indptr, int* __restrict__ cursor,
                           int n, int total) {
    int i = blockIdx.x * 256 + threadIdx.x;
    if (i == 0) indptr[n] = total;
    if (i >= n) return;
    int e = bsums[blockIdx.x] + pref[i];
    indptr[i] = e;
    cursor[i] = e;
}

__global__ void scatter_edges(const int* __restrict__ ei, int* __restrict__ cursor,
                              int* __restrict__ col, int E, int N) {
    int t = blockIdx.x * blockDim.x + threadIdx.x;
    if (t >= E + N) return;
    int src, dst;
    if (t < E) { src = ei[t]; dst = ei[E + t]; }
    else       { src = dst = t - E; }
    int pos = atomicAdd(&cursor[dst], 1);
    col[pos] = src;
}

// ---------------- fused one-shot weight prep --------------------------------
// bt layout per layer: bt[btOff + m*KA + h*Kp + k] = fp16(W[k*HC + h*C + m])
// wesed[weOff + k*2H + o] = sum_c W[k,h*C+c]*a[h,c]  (h=o%H, a=as/ad by o<H).
// wstack (layer 4, C=2): wstack[(h*Kp+k)*2+c] = W4[k*32 + h*2 + c].
__global__ __launch_bounds__(256) void prep_all(
        const float* __restrict__ W0, const float* __restrict__ W1,
        const float* __restrict__ W2, const float* __restrict__ W3,
        const float* __restrict__ W4,
        const float* __restrict__ as0, const float* __restrict__ as1,
        const float* __restrict__ as2, const float* __restrict__ as3,
        const float* __restrict__ as4,
        const float* __restrict__ ad0, const float* __restrict__ ad1,
        const float* __restrict__ ad2, const float* __restrict__ ad3,
        const float* __restrict__ ad4,
        unsigned short* __restrict__ bt, float* __restrict__ wesed,
        float* __restrict__ wstack) {
    const int Kc[5]  = {34, 64, 128, 256, 128};
    const int Kpc[5] = {48, 64, 128, 256, 128};
    const int Hc[5]  = {8, 16, 8, 8, 16};
    const int Cc[5]  = {64, 128, 256, 128, 2};
    const int HCc[5] = {512, 2048, 2048, 1024, 32};
    const int KAc[5] = {384, 1024, 1024, 2048, 2048};
    const int btOff[5] = {0, 24576, 155648, 417792, 679936};
    const int weOff[5] = {0, 768, 2816, 4864, 8960};

    int b = blockIdx.x, tid = threadIdx.x;

    if (b < 168) {
        // ---- LDS-tiled transpose, one (layer, head, 64x64 tile) per block --
        int lyr, tloc;
        if (b < 8)        { lyr = 0; tloc = b; }
        else if (b < 40)  { lyr = 1; tloc = b - 8; }
        else if (b < 104) { lyr = 2; tloc = b - 40; }
        else              { lyr = 3; tloc = b - 104; }
        const int ktl[4] = {1, 1, 2, 4};   // ceil(Kp/64)
        const int mtl[4] = {1, 2, 4, 2};   // ceil(C/64)
        int kt = ktl[lyr], mt = mtl[lyr];
        int per_h = kt * mt;
        int h = tloc / per_h, r = tloc - h * per_h;
        int ki = r % kt, mi = r / kt;
        int k0 = ki * 64, m0 = mi * 64;
        int K = Kc[lyr], Kp = Kpc[lyr], C = Cc[lyr], HC = HCc[lyr], KA = KAc[lyr];
        const float* W;
        if (lyr == 0) W = W0; else if (lyr == 1) W = W1;
        else if (lyr == 2) W = W2; else W = W3;

        __shared__ float tile[64][65];
        int c = tid & 63, rg = tid >> 6;
        for (int r2 = rg; r2 < 64; r2 += 4) {       // coalesced 256B reads
            int k = k0 + r2, m = m0 + c;
            float v = (k < K && m < C) ? W[(size_t)k * HC + h * C + m] : 0.f;
            tile[r2][c] = v;
        }
        __syncthreads();
        unsigned short* bp = bt + btOff[lyr];
        for (int mr = rg; mr < 64; mr += 4) {       // coalesced 128B fp16 writes
            int m = m0 + mr, k = k0 + c;
            if (m < C && k < Kp)
                bp[(size_t)m * KA + h * Kp + k] =
                    __half_as_ushort(__float2half(tile[c][mr]));
        }
    } else if (b < 184) {
        // ---- wstack for layer 4 (C=2): 4096 outputs ----
        int u = (b - 168) * 256 + tid;              // Kp=128, H=16, HC=32
        int cc = u & 1, rr = u >> 1;
        int h = rr >> 7, k = rr & 127;
        wstack[u] = W4[k * 32 + h * 2 + cc];
    } else {
        // ---- wesed dots: sizes {768,2048,2048,4096,4096} -> 51 blocks ----
        int wb = b - 184;
        int lyr, u0;
        if (wb < 3)       { lyr = 0; u0 = wb * 256; }
        else if (wb < 11) { lyr = 1; u0 = (wb - 3) * 256; }
        else if (wb < 19) { lyr = 2; u0 = (wb - 11) * 256; }
        else if (wb < 35) { lyr = 3; u0 = (wb - 19) * 256; }
        else              { lyr = 4; u0 = (wb - 35) * 256; }
        int u = u0 + tid;
        int K = Kc[lyr], Kp = Kpc[lyr], H = Hc[lyr], C = Cc[lyr], HC = HCc[lyr];
        int H2 = 2 * H;
        if (u < Kp * H2) {
            int k = u / H2, o = u - k * H2;
            float s = 0.f;
            if (k < K) {
                int h = (o < H) ? o : o - H;
                const float *W, *as_, *ad_;
                if (lyr == 0)      { W = W0; as_ = as0; ad_ = ad0; }
                else if (lyr == 1) { W = W1; as_ = as1; ad_ = ad1; }
                else if (lyr == 2) { W = W2; as_ = as2; ad_ = ad2; }
                else if (lyr == 3) { W = W3; as_ = as3; ad_ = ad3; }
                else               { W = W4; as_ = as4; ad_ = ad4; }
                const float* av = ((o < H) ? as_ : ad_) + h * C;
                const float* wp = W + (size_t)k * HC + h * C;
#pragma unroll 4
                for (int c2 = 0; c2 < C; ++c2) s += wp[c2] * av[c2];
            }
            wesed[weOff[lyr] + u] = s;
        }
    }
}

// ---------------- es/ed: esed[n, o] = hin16[n,:] @ wesed[:,o], o < 2H -------
__global__ void esed_kernel(const __half* __restrict__ hin, const float* __restrict__ wesed,
                            float* __restrict__ esed, int N, int Kp, int H2) {
    int t = blockIdx.x * blockDim.x + threadIdx.x;
    if (t >= N * H2) return;
    int n = t / H2, o = t - n * H2;
    const __half2* hp = (const __half2*)(hin + (size_t)n * Kp);
    float s = 0.f;
    for (int k2 = 0; k2 < Kp / 2; ++k2) {
        float2 f = __half22float2(hp[k2]);
        s += f.x * wesed[(2 * k2) * H2 + o] + f.y * wesed[(2 * k2 + 1) * H2 + o];
    }
    esed[t] = s;
}

// -------- attention: single pass, 4-deep gather pipeline --------------------
__global__ void attn_kernel(const float* __restrict__ esed,
                            const int* __restrict__ indptr, const int* __restrict__ col,
                            float* __restrict__ palpha, float* __restrict__ zinv,
                            int N, int H) {
    int t = blockIdx.x * blockDim.x + threadIdx.x;
    if (t >= N * H) return;
    int n = t / H, h = t - n * H;
    int H2 = 2 * H;
    float edv = esed[n * H2 + H + h];
    int beg = indptr[n], end = indptr[n + 1];
    float z = 0.f;
    int i = beg;
    for (; i + 3 < end; i += 4) {
        int s0 = col[i], s1 = col[i + 1], s2 = col[i + 2], s3 = col[i + 3];
        float e0 = esed[s0 * H2 + h];
        float e1 = esed[s1 * H2 + h];
        float e2 = esed[s2 * H2 + h];
        float e3 = esed[s3 * H2 + h];
        float p0 = expf(lrelu02(e0 + edv));
        float p1 = expf(lrelu02(e1 + edv));
        float p2 = expf(lrelu02(e2 + edv));
        float p3 = expf(lrelu02(e3 + edv));
        palpha[(size_t)(i + 0) * H + h] = p0;
        palpha[(size_t)(i + 1) * H + h] = p1;
        palpha[(size_t)(i + 2) * H + h] = p2;
        palpha[(size_t)(i + 3) * H + h] = p3;
        z += p0; z += p1; z += p2; z += p3;
    }
    for (; i < end; ++i) {
        float e = lrelu02(esed[col[i] * H2 + h] + edv);
        float p = expf(e);
        palpha[(size_t)i * H + h] = p;
        z += p;
    }
    zinv[t] = (1.f / H) / (z + 1e-16f);
}

// -------- gather: 4-deep hin pipeline ---------------------------------------
template <int H, int KP, int NPB>
__global__ __launch_bounds__(NPB * KP / 2) void gat_gather(
        const __half* __restrict__ hinf, const float* __restrict__ palpha,
        const float* __restrict__ zinv, const int* __restrict__ indptr,
        const int* __restrict__ col, __half* __restrict__ g, int N) {
    const int TPN = KP / 2;
    int sub = threadIdx.x / TPN;
    int j   = threadIdx.x % TPN;
    int n = blockIdx.x * NPB + sub;
    if (n >= N) return;
    int c0 = j * 2;
    float acc[H][2];
#pragma unroll
    for (int h = 0; h < H; ++h) { acc[h][0] = 0.f; acc[h][1] = 0.f; }
    int beg = indptr[n], end = indptr[n + 1];
    int i = beg;
    for (; i + 3 < end; i += 4) {
        int s0 = col[i], s1 = col[i + 1], s2 = col[i + 2], s3 = col[i + 3];
        __half2 hv0 = *(const __half2*)(hinf + (size_t)s0 * KP + c0);
        __half2 hv1 = *(const __half2*)(hinf + (size_t)s1 * KP + c0);
        __half2 hv2 = *(const __half2*)(hinf + (size_t)s2 * KP + c0);
        __half2 hv3 = *(const __half2*)(hinf + (size_t)s3 * KP + c0);
        float2 fv[4] = {__half22float2(hv0), __half22float2(hv1),
                        __half22float2(hv2), __half22float2(hv3)};
#pragma unroll
        for (int e = 0; e < 4; ++e) {
            const float2* ap = (const float2*)(palpha + (size_t)(i + e) * H);
            float2 f = fv[e];
#pragma unroll
            for (int h2 = 0; h2 < H / 2; ++h2) {
                float2 aa = ap[h2];
                acc[2 * h2 + 0][0] += aa.x * f.x;
                acc[2 * h2 + 0][1] += aa.x * f.y;
                acc[2 * h2 + 1][0] += aa.y * f.x;
                acc[2 * h2 + 1][1] += aa.y * f.y;
            }
        }
    }
    for (; i < end; ++i) {
        int src = col[i];
        __half2 hv = *(const __half2*)(hinf + (size_t)src * KP + c0);
        float2 f = __half22float2(hv);
        const float2* ap = (const float2*)(palpha + (size_t)i * H);
#pragma unroll
        for (int h2 = 0; h2 < H / 2; ++h2) {
            float2 aa = ap[h2];
            acc[2 * h2 + 0][0] += aa.x * f.x;
            acc[2 * h2 + 0][1] += aa.x * f.y;
            acc[2 * h2 + 1][0] += aa.y * f.x;
            acc[2 * h2 + 1][1] += aa.y * f.y;
        }
    }
    __half* gp = g + (size_t)n * (H * KP) + c0;
#pragma unroll
    for (int h = 0; h < H; ++h) {
        float zf = zinv[n * H + h];
        *(__half2*)(gp + h * KP) = __floats2half2_rn(acc[h][0] * zf, acc[h][1] * zf);
    }
}

// ---------------- single-pass f16 MFMA GEMM, JT col-tiles in registers ------
// 1 wave per 16 rows; grid = (ceil(N/16), M/(16*JT)). A read once per
// col-block; B (<=256KB) L2-resident. Fused bias/selu/mask epilogue -> O16.
template <int JT>
__global__ __launch_bounds__(64) void gemm_sw(const __half* __restrict__ A,
                                              const unsigned short* __restrict__ Bhi,
                                              const float* __restrict__ bias,
                                              const unsigned* __restrict__ masks,
                                              __half* __restrict__ O16,
                                              int N, int K, int M) {
    int lane = threadIdx.x;
    int ln16 = lane & 15;
    int q    = lane >> 4;                 // 0..3 (k-octet)
    int row0 = blockIdx.x * 16;
    int col0 = blockIdx.y * (16 * JT);

    const __half* ap = A + (size_t)(row0 + ln16) * K + q * 8;
    const unsigned short* bhp = Bhi + (size_t)(col0 + ln16) * K + q * 8;
    const size_t cstep = (size_t)16 * K;

    f32x4 acc[JT];
#pragma unroll
    for (int j = 0; j < JT; ++j) acc[j] = (f32x4){0.f, 0.f, 0.f, 0.f};

#pragma unroll 2
    for (int kc = 0; kc < K; kc += 32) {
        half8 a = *(const half8*)(ap + kc);
        half8 bh[JT];
#pragma unroll
        for (int j = 0; j < JT; ++j)
            bh[j] = *(const half8*)(bhp + (size_t)j * cstep + kc);
#pragma unroll
        for (int j = 0; j < JT; ++j)
            acc[j] = __builtin_amdgcn_mfma_f32_16x16x32_f16(a, bh[j], acc[j], 0, 0, 0);
    }

    // C/D layout: col = lane&15, row = (lane>>4)*4 + reg
#pragma unroll
    for (int j = 0; j < JT; ++j) {
        int cc = col0 + j * 16 + ln16;
        float bv = bias[cc];
#pragma unroll
        for (int r = 0; r < 4; ++r) {
            int rr = row0 + q * 4 + r;
            if (rr >= N) continue;
            float v = selu_f(acc[j][r] + bv);
            if (cc < 2) {
                unsigned mk = masks[rr];
                if (cc == 0) { if (mk & 2u) v = 0.f; else if (mk & 1u) v = 1.f; }
                else         { if (mk & 8u) v = 1.f; else if (mk & 4u) v = 0.f; }
            }
            O16[(size_t)rr * M + cc] = __float2half(v);
        }
    }
}

// ---------------- final layer (C=2): out = bfix(x + selu(g @ W5s + b5)) -----
__global__ __launch_bounds__(256) void final5_kernel(const __half* __restrict__ g,
                                                     const float* __restrict__ W5,
                                                     const float* __restrict__ b5,
                                                     const unsigned* __restrict__ masks,
                                                     const float* __restrict__ x,
                                                     float* __restrict__ out,
                                                     int N, int KA) {
    int wave = threadIdx.x >> 6, lane = threadIdx.x & 63;
    int n = blockIdx.x * 4 + wave;
    if (n >= N) return;
    float a0 = 0.f, a1 = 0.f;
    const __half* gp = g + (size_t)n * KA;
    for (int k = lane * 2; k < KA; k += 128) {
        float2 f = __half22float2(*(const __half2*)(gp + k));
        float4 w = *(const float4*)(W5 + (size_t)k * 2);
        a0 += f.x * w.x + f.y * w.z;
        a1 += f.x * w.y + f.y * w.w;
    }
#pragma unroll
    for (int off = 32; off >= 1; off >>= 1) {
        a0 += __shfl_xor(a0, off);
        a1 += __shfl_xor(a1, off);
    }
    if (lane == 0) {
        unsigned mk = masks[n];
        float v0 = x[n * 10 + 0] + selu_f(a0 + b5[0]);
        float v1 = x[n * 10 + 1] + selu_f(a1 + b5[1]);
        if (mk & 2u) v0 = 0.f; else if (mk & 1u) v0 = 1.f;
        if (mk & 8u) v1 = 1.f; else if (mk & 4u) v1 = 0.f;
        out[n * 2 + 0] = v0;
        out[n * 2 + 1] = v1;
    }
}

// ---------------------------------------------------------------------------
extern "C" void kernel_launch(void* const* d_in, const int* in_sizes, int n_in,
                              void* d_out, int out_size, void* d_ws, size_t ws_size,
                              hipStream_t stream) {
    const float* x   = (const float*)d_in[0];
    const int*   ei  = (const int*)d_in[1];
    const float* cf  = (const float*)d_in[2];
    const float* cw[4] = {(const float*)d_in[3], (const float*)d_in[5],
                          (const float*)d_in[7], (const float*)d_in[9]};
    const float* cb[4] = {(const float*)d_in[4], (const float*)d_in[6],
                          (const float*)d_in[8], (const float*)d_in[10]};
    const float* gw[5], *gas[5], *gad[5], *gb[5];
    for (int i = 0; i < 5; ++i) {
        gw[i]  = (const float*)d_in[11 + 4 * i];
        gas[i] = (const float*)d_in[12 + 4 * i];
        gad[i] = (const float*)d_in[13 + 4 * i];
        gb[i]  = (const float*)d_in[14 + 4 * i];
    }
    const int N = in_sizes[0] / 10;        // 10000
    const int E = in_sizes[1] / 2;         // 160000
    const int EN = E + N;
    const int NB = (N + 255) / 256;        // scan blocks (40)

    // ---- workspace carve-up ----
    char* base = (char*)d_ws;
    size_t off = 0;
    auto alloc = [&](size_t bytes) -> char* {
        char* p = base + off;
        off = (off + bytes + 255) & ~(size_t)255;
        return p;
    };
    float* cfp   = (float*)alloc((size_t)4 * PSZ * 4);
    float* c1p   = (float*)alloc((size_t)16 * PSZ * 4);
    float* c2p   = (float*)alloc((size_t)32 * PSZ * 4);
    float* c3p   = (float*)alloc((size_t)64 * PSZ * 4);
    float* c4p   = (float*)alloc((size_t)24 * PSZ * 4);
    float* gfeat = (float*)alloc(24 * 4);
    __half* hA16 = (__half*)alloc((size_t)N * 256 * 2);
    __half* hB16 = (__half*)alloc((size_t)N * 256 * 2);
    __half* g    = (__half*)alloc((size_t)N * 2048 * 2);
    float* esed  = (float*)alloc((size_t)N * 32 * 4);
    float* zinv  = (float*)alloc((size_t)N * 16 * 4);
    float* palpha = (float*)alloc((size_t)EN * 16 * 4);      // fp32 numerators
    float* wesed = (float*)alloc((size_t)13056 * 4);         // all 5 layers
    float* wstack= (float*)alloc((size_t)2048 * 2 * 4);
    unsigned short* bt = (unsigned short*)alloc((size_t)679936 * 2);  // all 4 GEMM layers
    unsigned* masks = (unsigned*)alloc((size_t)N * 4);
    int* cnt    = (int*)alloc((size_t)N * 4);
    int* pref   = (int*)alloc((size_t)N * 4);
    int* bsums  = (int*)alloc(64 * 4);
    int* indptr = (int*)alloc((size_t)(N + 1) * 4);
    int* cursor = (int*)alloc((size_t)N * 4);
    int* col    = (int*)alloc((size_t)EN * 4);
    (void)ws_size; // ~78 MB

    // ---- one-shot fused weight prep (all 5 layers) ----
    prep_all<<<235, 256, 0, stream>>>(gw[0], gw[1], gw[2], gw[3], gw[4],
                                      gas[0], gas[1], gas[2], gas[3], gas[4],
                                      gad[0], gad[1], gad[2], gad[3], gad[4],
                                      bt, wesed, wstack);

    // ---- CNN (padded layout; single memset zeroes all borders) ----
    hipMemsetAsync(cfp, 0, (size_t)140 * PSZ * 4, stream);
    pad_input<<<(4 * 4096 + 255) / 256, 256, 0, stream>>>(cf, cfp);
    conv3x3_pad<4><<<dim3(16, 16), 256, 0, stream>>>(cfp, cw[0], cb[0], c1p);
    conv3x3_pad<16><<<dim3(16, 32), 256, 0, stream>>>(c1p, cw[1], cb[1], c2p);
    conv3x3_pad<32><<<dim3(16, 64), 256, 0, stream>>>(c2p, cw[2], cb[2], c3p);
    conv3x3_pad<64><<<dim3(16, 24), 256, 0, stream>>>(c3p, cw[3], cb[3], c4p);
    avgpool_c<<<24, 256, 0, stream>>>(c4p, gfeat);

    // ---- h0 (padded to 48, fp16) + masks ----
    build_h0<<<(N + 255) / 256, 256, 0, stream>>>(x, gfeat, hA16, masks, N);

    // ---- CSR by dst (incl self loops), parallel scan ----
    hipMemsetAsync(cnt, 0, (size_t)N * 4, stream);
    count_dst<<<(EN + 255) / 256, 256, 0, stream>>>(ei, cnt, E, N);
    scan_blocks<<<NB, 256, 0, stream>>>(cnt, pref, bsums, N);
    scan_sums<<<1, 64, 0, stream>>>(bsums, NB);
    scan_apply<<<NB, 256, 0, stream>>>(pref, bsums, indptr, cursor, N, EN);
    scatter_edges<<<(EN + 255) / 256, 256, 0, stream>>>(ei, cursor, col, E, N);

    // ---- GAT layers ----
    const int Kp[5] = {48, 64, 128, 256, 128};   // padded input dims
    const int Hs[5] = {8, 16, 8, 8, 16};
    const int Cs[5] = {64, 128, 256, 128, 2};
    const int btOffA[5] = {0, 24576, 155648, 417792, 0};
    const int weOffA[5] = {0, 768, 2816, 4864, 8960};

    const __half* hin16 = hA16;
    __half* hout16[4]  = {hB16, hA16, hB16, hA16};

    for (int lyr = 0; lyr < 5; ++lyr) {
        int KP = Kp[lyr], H = Hs[lyr], C = Cs[lyr];
        int KA = H * KP;
        esed_kernel<<<(N * 2 * H + 255) / 256, 256, 0, stream>>>(hin16, wesed + weOffA[lyr],
                                                                 esed, N, KP, 2 * H);
        attn_kernel<<<(N * H + 255) / 256, 256, 0, stream>>>(esed, indptr, col,
                                                             palpha, zinv, N, H);
        if (lyr == 0)
            gat_gather<8, 48, 10><<<(N + 9) / 10, 240, 0, stream>>>(hin16, palpha, zinv, indptr, col, g, N);
        else if (lyr == 1)
            gat_gather<16, 64, 8><<<(N + 7) / 8, 256, 0, stream>>>(hin16, palpha, zinv, indptr, col, g, N);
        else if (lyr == 2)
            gat_gather<8, 128, 4><<<(N + 3) / 4, 256, 0, stream>>>(hin16, palpha, zinv, indptr, col, g, N);
        else if (lyr == 3)
            gat_gather<8, 256, 2><<<(N + 1) / 2, 256, 0, stream>>>(hin16, palpha, zinv, indptr, col, g, N);
        else
            gat_gather<16, 128, 4><<<(N + 3) / 4, 256, 0, stream>>>(hin16, palpha, zinv, indptr, col, g, N);

        if (lyr < 4) {
            const unsigned short* btL = bt + btOffA[lyr];
            int gx = (N + 15) / 16;
            if (lyr == 0) {            // KA=384,  C=64 : JT=4, grid (625,1)
                gemm_sw<4><<<dim3(gx, 1), 64, 0, stream>>>(g, btL, gb[lyr], masks, hout16[lyr], N, KA, C);
            } else if (lyr == 1) {     // KA=1024, C=128: JT=8, grid (625,1)
                gemm_sw<8><<<dim3(gx, 1), 64, 0, stream>>>(g, btL, gb[lyr], masks, hout16[lyr], N, KA, C);
            } else if (lyr == 2) {     // KA=1024, C=256: JT=8, grid (625,2)
                gemm_sw<8><<<dim3(gx, 2), 64, 0, stream>>>(g, btL, gb[lyr], masks, hout16[lyr], N, KA, C);
            } else {                   // KA=2048, C=128: JT=8, grid (625,1)
                gemm_sw<8><<<dim3(gx, 1), 64, 0, stream>>>(g, btL, gb[lyr], masks, hout16[lyr], N, KA, C);
            }
            hin16 = hout16[lyr];
        } else {
            final5_kernel<<<(N + 3) / 4, 256, 0, stream>>>(g, wstack, gb[4], masks, x,
                                                           (float*)d_out, N, KA);
        }
    }
}

// Round 3
// 616.341 us; speedup vs baseline: 1.0391x; 1.0391x over previous
//
#include <hip/hip_runtime.h>
#include <hip/hip_fp16.h>
#include <math.h>

// ---------------------------------------------------------------------------
// NetGlobGATFix. R19: fix gemm occupancy collapse from R18.
//   - R18's gemm_sw: 625 waves total, 1 wave/block -> 5.6% occupancy,
//     latency-bound, 59.7us/layer (worse than split-K it replaced).
//   - gemm_kr<JT=4>: 256-thr blocks, 4 waves split K in-block, LDS reduce,
//     fused epilogue. Grid (N/16, C/64) -> 2500..10000 waves, A read once
//     per col-block, B L2-resident, still no global partial round-trip.
//   - Everything else identical to R18 (conv split kept; R17 was 609us).
// ---------------------------------------------------------------------------

#define DEVFN static __device__ __forceinline__

typedef __attribute__((ext_vector_type(8))) _Float16 half8;
typedef __attribute__((ext_vector_type(4))) float f32x4;

DEVFN float selu_f(float v) {
    const float scale = 1.0507009873554805f;
    const float alpha = 1.6732632423543772f;
    return v > 0.f ? scale * v : scale * alpha * (expf(v) - 1.f);
}

DEVFN float lrelu02(float v) { return v > 0.f ? v : 0.2f * v; }

// ---------------- CNN (padded 66x66 layout) ----------------
#define PST 66
#define PSZ (66 * 66)

__global__ void pad_input(const float* __restrict__ cf, float* __restrict__ out) {
    int t = blockIdx.x * blockDim.x + threadIdx.x;
    if (t >= 4 * 4096) return;
    int c = t >> 12, pix = t & 4095;
    int y = pix >> 6, x = pix & 63;
    out[c * PSZ + (y + 1) * PST + (x + 1)] = cf[t];
}

template <int CIN>
__global__ __launch_bounds__(256) void conv3x3_pad(const float* __restrict__ in,
                                                   const float* __restrict__ w,
                                                   const float* __restrict__ b,
                                                   float* __restrict__ out) {
    int x  = threadIdx.x & 63;
    int yg = threadIdx.x >> 6;
    int y  = blockIdx.x * 4 + yg;          // 0..63
    int co = blockIdx.y;
    float acc = b[co];
    const float* wp = w + (size_t)co * CIN * 9;
#pragma unroll 4
    for (int ci = 0; ci < CIN; ++ci) {
        const float* ip = in + ci * PSZ + y * PST + x;
        const float* wr = wp + ci * 9;
        acc += wr[0] * ip[0]           + wr[1] * ip[1]           + wr[2] * ip[2]
             + wr[3] * ip[PST]         + wr[4] * ip[PST + 1]     + wr[5] * ip[PST + 2]
             + wr[6] * ip[2 * PST]     + wr[7] * ip[2 * PST + 1] + wr[8] * ip[2 * PST + 2];
    }
    out[(size_t)co * PSZ + (y + 1) * PST + (x + 1)] = selu_f(acc);
}

__global__ void avgpool_c(const float* __restrict__ in, float* __restrict__ gfeat) {
    int c = blockIdx.x;            // 24 blocks
    int t = threadIdx.x;           // 256 threads
    float s = 0.f;
    for (int i = t; i < 4096; i += 256) {
        int y = i >> 6, x = i & 63;
        s += in[c * PSZ + (y + 1) * PST + (x + 1)];
    }
#pragma unroll
    for (int off = 32; off >= 1; off >>= 1) s += __shfl_xor(s, off);
    __shared__ float red[4];
    int wave = t >> 6, lane = t & 63;
    if (lane == 0) red[wave] = s;
    __syncthreads();
    if (t == 0) gfeat[c] = (red[0] + red[1] + red[2] + red[3]) * (1.f / 4096.f);
}

// ---------------- node feature init (padded to 48 ch, fp16) + masks ---------
__global__ void build_h0(const float* __restrict__ x, const float* __restrict__ gfeat,
                         __half* __restrict__ h0f, unsigned* __restrict__ masks, int N) {
    int n = blockIdx.x * blockDim.x + threadIdx.x;
    if (n >= N) return;
    float x0 = x[n * 10 + 0], x1 = x[n * 10 + 1];
    unsigned mk = (x0 == 1.f ? 1u : 0u) | (x0 == 0.f ? 2u : 0u) |
                  (x1 == 0.f ? 4u : 0u) | (x1 == 1.f ? 8u : 0u);
    masks[n] = mk;
    __half* hq = h0f + (size_t)n * 48;
#pragma unroll
    for (int j = 0; j < 48; ++j) {
        float v = (j < 24) ? gfeat[j] : (j < 34 ? x[n * 10 + (j - 24)] : 0.f);
        hq[j] = __float2half(v);
    }
}

// ---------------- CSR build (parallel scan) ----------------
__global__ void count_dst(const int* __restrict__ ei, int* __restrict__ cnt, int E, int N) {
    int t = blockIdx.x * blockDim.x + threadIdx.x;
    if (t >= E + N) return;
    int dst = (t < E) ? ei[E + t] : (t - E);
    atomicAdd(&cnt[dst], 1);
}

__global__ void scan_blocks(const int* __restrict__ cnt, int* __restrict__ pref,
                            int* __restrict__ bsums, int n) {
    __shared__ int sdata[256];
    int i = blockIdx.x * 256 + threadIdx.x;
    int v = (i < n) ? cnt[i] : 0;
    sdata[threadIdx.x] = v;
    __syncthreads();
    for (int off = 1; off < 256; off <<= 1) {
        int tmp = (threadIdx.x >= off) ? sdata[threadIdx.x - off] : 0;
        __syncthreads();
        sdata[threadIdx.x] += tmp;
        __syncthreads();
    }
    if (i < n) pref[i] = sdata[threadIdx.x] - v;
    if (threadIdx.x == 255) bsums[blockIdx.x] = sdata[255];
}

__global__ void scan_sums(int* __restrict__ bsums, int nb) {
    int tid = threadIdx.x;                 // 64
    int orig = (tid < nb) ? bsums[tid] : 0;
    int v = orig;
#pragma unroll
    for (int off = 1; off < 64; off <<= 1) {
        int u = __shfl_up(v, off);
        if (tid >= off) v += u;
    }
    if (tid < nb) bsums[tid] = v - orig;
}

__global__ void scan_apply(const int* __restrict__ pref, const int* __restrict__ bsums,
                           int* __restrict__ indptr, int* __restrict__ cursor,
                           int n, int total) {
    int i = blockIdx.x * 256 + threadIdx.x;
    if (i == 0) indptr[n] = total;
    if (i >= n) return;
    int e = bsums[blockIdx.x] + pref[i];
    indptr[i] = e;
    cursor[i] = e;
}

__global__ void scatter_edges(const int* __restrict__ ei, int* __restrict__ cursor,
                              int* __restrict__ col, int E, int N) {
    int t = blockIdx.x * blockDim.x + threadIdx.x;
    if (t >= E + N) return;
    int src, dst;
    if (t < E) { src = ei[t]; dst = ei[E + t]; }
    else       { src = dst = t - E; }
    int pos = atomicAdd(&cursor[dst], 1);
    col[pos] = src;
}

// ---------------- fused one-shot weight prep --------------------------------
// bt layout per layer: bt[btOff + m*KA + h*Kp + k] = fp16(W[k*HC + h*C + m])
// wesed[weOff + k*2H + o] = sum_c W[k,h*C+c]*a[h,c]  (h=o%H, a=as/ad by o<H).
// wstack (layer 4, C=2): wstack[(h*Kp+k)*2+c] = W4[k*32 + h*2 + c].
__global__ __launch_bounds__(256) void prep_all(
        const float* __restrict__ W0, const float* __restrict__ W1,
        const float* __restrict__ W2, const float* __restrict__ W3,
        const float* __restrict__ W4,
        const float* __restrict__ as0, const float* __restrict__ as1,
        const float* __restrict__ as2, const float* __restrict__ as3,
        const float* __restrict__ as4,
        const float* __restrict__ ad0, const float* __restrict__ ad1,
        const float* __restrict__ ad2, const float* __restrict__ ad3,
        const float* __restrict__ ad4,
        unsigned short* __restrict__ bt, float* __restrict__ wesed,
        float* __restrict__ wstack) {
    const int Kc[5]  = {34, 64, 128, 256, 128};
    const int Kpc[5] = {48, 64, 128, 256, 128};
    const int Hc[5]  = {8, 16, 8, 8, 16};
    const int Cc[5]  = {64, 128, 256, 128, 2};
    const int HCc[5] = {512, 2048, 2048, 1024, 32};
    const int KAc[5] = {384, 1024, 1024, 2048, 2048};
    const int btOff[5] = {0, 24576, 155648, 417792, 679936};
    const int weOff[5] = {0, 768, 2816, 4864, 8960};

    int b = blockIdx.x, tid = threadIdx.x;

    if (b < 168) {
        // ---- LDS-tiled transpose, one (layer, head, 64x64 tile) per block --
        int lyr, tloc;
        if (b < 8)        { lyr = 0; tloc = b; }
        else if (b < 40)  { lyr = 1; tloc = b - 8; }
        else if (b < 104) { lyr = 2; tloc = b - 40; }
        else              { lyr = 3; tloc = b - 104; }
        const int ktl[4] = {1, 1, 2, 4};   // ceil(Kp/64)
        const int mtl[4] = {1, 2, 4, 2};   // ceil(C/64)
        int kt = ktl[lyr], mt = mtl[lyr];
        int per_h = kt * mt;
        int h = tloc / per_h, r = tloc - h * per_h;
        int ki = r % kt, mi = r / kt;
        int k0 = ki * 64, m0 = mi * 64;
        int K = Kc[lyr], Kp = Kpc[lyr], C = Cc[lyr], HC = HCc[lyr], KA = KAc[lyr];
        const float* W;
        if (lyr == 0) W = W0; else if (lyr == 1) W = W1;
        else if (lyr == 2) W = W2; else W = W3;

        __shared__ float tile[64][65];
        int c = tid & 63, rg = tid >> 6;
        for (int r2 = rg; r2 < 64; r2 += 4) {       // coalesced 256B reads
            int k = k0 + r2, m = m0 + c;
            float v = (k < K && m < C) ? W[(size_t)k * HC + h * C + m] : 0.f;
            tile[r2][c] = v;
        }
        __syncthreads();
        unsigned short* bp = bt + btOff[lyr];
        for (int mr = rg; mr < 64; mr += 4) {       // coalesced 128B fp16 writes
            int m = m0 + mr, k = k0 + c;
            if (m < C && k < Kp)
                bp[(size_t)m * KA + h * Kp + k] =
                    __half_as_ushort(__float2half(tile[c][mr]));
        }
    } else if (b < 184) {
        // ---- wstack for layer 4 (C=2): 4096 outputs ----
        int u = (b - 168) * 256 + tid;              // Kp=128, H=16, HC=32
        int cc = u & 1, rr = u >> 1;
        int h = rr >> 7, k = rr & 127;
        wstack[u] = W4[k * 32 + h * 2 + cc];
    } else {
        // ---- wesed dots: sizes {768,2048,2048,4096,4096} -> 51 blocks ----
        int wb = b - 184;
        int lyr, u0;
        if (wb < 3)       { lyr = 0; u0 = wb * 256; }
        else if (wb < 11) { lyr = 1; u0 = (wb - 3) * 256; }
        else if (wb < 19) { lyr = 2; u0 = (wb - 11) * 256; }
        else if (wb < 35) { lyr = 3; u0 = (wb - 19) * 256; }
        else              { lyr = 4; u0 = (wb - 35) * 256; }
        int u = u0 + tid;
        int K = Kc[lyr], Kp = Kpc[lyr], H = Hc[lyr], C = Cc[lyr], HC = HCc[lyr];
        int H2 = 2 * H;
        if (u < Kp * H2) {
            int k = u / H2, o = u - k * H2;
            float s = 0.f;
            if (k < K) {
                int h = (o < H) ? o : o - H;
                const float *W, *as_, *ad_;
                if (lyr == 0)      { W = W0; as_ = as0; ad_ = ad0; }
                else if (lyr == 1) { W = W1; as_ = as1; ad_ = ad1; }
                else if (lyr == 2) { W = W2; as_ = as2; ad_ = ad2; }
                else if (lyr == 3) { W = W3; as_ = as3; ad_ = ad3; }
                else               { W = W4; as_ = as4; ad_ = ad4; }
                const float* av = ((o < H) ? as_ : ad_) + h * C;
                const float* wp = W + (size_t)k * HC + h * C;
#pragma unroll 4
                for (int c2 = 0; c2 < C; ++c2) s += wp[c2] * av[c2];
            }
            wesed[weOff[lyr] + u] = s;
        }
    }
}

// ---------------- es/ed: esed[n, o] = hin16[n,:] @ wesed[:,o], o < 2H -------
__global__ void esed_kernel(const __half* __restrict__ hin, const float* __restrict__ wesed,
                            float* __restrict__ esed, int N, int Kp, int H2) {
    int t = blockIdx.x * blockDim.x + threadIdx.x;
    if (t >= N * H2) return;
    int n = t / H2, o = t - n * H2;
    const __half2* hp = (const __half2*)(hin + (size_t)n * Kp);
    float s = 0.f;
    for (int k2 = 0; k2 < Kp / 2; ++k2) {
        float2 f = __half22float2(hp[k2]);
        s += f.x * wesed[(2 * k2) * H2 + o] + f.y * wesed[(2 * k2 + 1) * H2 + o];
    }
    esed[t] = s;
}

// -------- attention: single pass, 4-deep gather pipeline --------------------
__global__ void attn_kernel(const float* __restrict__ esed,
                            const int* __restrict__ indptr, const int* __restrict__ col,
                            float* __restrict__ palpha, float* __restrict__ zinv,
                            int N, int H) {
    int t = blockIdx.x * blockDim.x + threadIdx.x;
    if (t >= N * H) return;
    int n = t / H, h = t - n * H;
    int H2 = 2 * H;
    float edv = esed[n * H2 + H + h];
    int beg = indptr[n], end = indptr[n + 1];
    float z = 0.f;
    int i = beg;
    for (; i + 3 < end; i += 4) {
        int s0 = col[i], s1 = col[i + 1], s2 = col[i + 2], s3 = col[i + 3];
        float e0 = esed[s0 * H2 + h];
        float e1 = esed[s1 * H2 + h];
        float e2 = esed[s2 * H2 + h];
        float e3 = esed[s3 * H2 + h];
        float p0 = expf(lrelu02(e0 + edv));
        float p1 = expf(lrelu02(e1 + edv));
        float p2 = expf(lrelu02(e2 + edv));
        float p3 = expf(lrelu02(e3 + edv));
        palpha[(size_t)(i + 0) * H + h] = p0;
        palpha[(size_t)(i + 1) * H + h] = p1;
        palpha[(size_t)(i + 2) * H + h] = p2;
        palpha[(size_t)(i + 3) * H + h] = p3;
        z += p0; z += p1; z += p2; z += p3;
    }
    for (; i < end; ++i) {
        float e = lrelu02(esed[col[i] * H2 + h] + edv);
        float p = expf(e);
        palpha[(size_t)i * H + h] = p;
        z += p;
    }
    zinv[t] = (1.f / H) / (z + 1e-16f);
}

// -------- gather: 4-deep hin pipeline ---------------------------------------
template <int H, int KP, int NPB>
__global__ __launch_bounds__(NPB * KP / 2) void gat_gather(
        const __half* __restrict__ hinf, const float* __restrict__ palpha,
        const float* __restrict__ zinv, const int* __restrict__ indptr,
        const int* __restrict__ col, __half* __restrict__ g, int N) {
    const int TPN = KP / 2;
    int sub = threadIdx.x / TPN;
    int j   = threadIdx.x % TPN;
    int n = blockIdx.x * NPB + sub;
    if (n >= N) return;
    int c0 = j * 2;
    float acc[H][2];
#pragma unroll
    for (int h = 0; h < H; ++h) { acc[h][0] = 0.f; acc[h][1] = 0.f; }
    int beg = indptr[n], end = indptr[n + 1];
    int i = beg;
    for (; i + 3 < end; i += 4) {
        int s0 = col[i], s1 = col[i + 1], s2 = col[i + 2], s3 = col[i + 3];
        __half2 hv0 = *(const __half2*)(hinf + (size_t)s0 * KP + c0);
        __half2 hv1 = *(const __half2*)(hinf + (size_t)s1 * KP + c0);
        __half2 hv2 = *(const __half2*)(hinf + (size_t)s2 * KP + c0);
        __half2 hv3 = *(const __half2*)(hinf + (size_t)s3 * KP + c0);
        float2 fv[4] = {__half22float2(hv0), __half22float2(hv1),
                        __half22float2(hv2), __half22float2(hv3)};
#pragma unroll
        for (int e = 0; e < 4; ++e) {
            const float2* ap = (const float2*)(palpha + (size_t)(i + e) * H);
            float2 f = fv[e];
#pragma unroll
            for (int h2 = 0; h2 < H / 2; ++h2) {
                float2 aa = ap[h2];
                acc[2 * h2 + 0][0] += aa.x * f.x;
                acc[2 * h2 + 0][1] += aa.x * f.y;
                acc[2 * h2 + 1][0] += aa.y * f.x;
                acc[2 * h2 + 1][1] += aa.y * f.y;
            }
        }
    }
    for (; i < end; ++i) {
        int src = col[i];
        __half2 hv = *(const __half2*)(hinf + (size_t)src * KP + c0);
        float2 f = __half22float2(hv);
        const float2* ap = (const float2*)(palpha + (size_t)i * H);
#pragma unroll
        for (int h2 = 0; h2 < H / 2; ++h2) {
            float2 aa = ap[h2];
            acc[2 * h2 + 0][0] += aa.x * f.x;
            acc[2 * h2 + 0][1] += aa.x * f.y;
            acc[2 * h2 + 1][0] += aa.y * f.x;
            acc[2 * h2 + 1][1] += aa.y * f.y;
        }
    }
    __half* gp = g + (size_t)n * (H * KP) + c0;
#pragma unroll
    for (int h = 0; h < H; ++h) {
        float zf = zinv[n * H + h];
        *(__half2*)(gp + h * KP) = __floats2half2_rn(acc[h][0] * zf, acc[h][1] * zf);
    }
}

// ---------------- in-block split-K f16 MFMA GEMM ----------------------------
// 256 threads = 4 waves; wave w computes K-slice w of a 16-row x 64-col tile.
// LDS reduce across waves, fused bias/selu/mask epilogue -> O16.
// Grid = (ceil(N/16), M/64). No global partials.
template <int JT>
__global__ __launch_bounds__(256) void gemm_kr(const __half* __restrict__ A,
                                               const unsigned short* __restrict__ Bhi,
                                               const float* __restrict__ bias,
                                               const unsigned* __restrict__ masks,
                                               __half* __restrict__ O16,
                                               int N, int K, int M) {
    int tid  = threadIdx.x;
    int wave = tid >> 6, lane = tid & 63;
    int ln16 = lane & 15;
    int q    = lane >> 4;                 // 0..3 (k-octet)
    int row0 = blockIdx.x * 16;
    int col0 = blockIdx.y * (16 * JT);
    int ksl  = K >> 2;                    // K/4, multiple of 32 for all layers
    int kb   = wave * ksl, ke = kb + ksl;

    const __half* ap = A + (size_t)(row0 + ln16) * K + q * 8;
    const unsigned short* bhp = Bhi + (size_t)(col0 + ln16) * K + q * 8;
    const size_t cstep = (size_t)16 * K;

    f32x4 acc[JT];
#pragma unroll
    for (int j = 0; j < JT; ++j) acc[j] = (f32x4){0.f, 0.f, 0.f, 0.f};

#pragma unroll 2
    for (int kc = kb; kc < ke; kc += 32) {
        half8 a = *(const half8*)(ap + kc);
        half8 bh[JT];
#pragma unroll
        for (int j = 0; j < JT; ++j)
            bh[j] = *(const half8*)(bhp + (size_t)j * cstep + kc);
#pragma unroll
        for (int j = 0; j < JT; ++j)
            acc[j] = __builtin_amdgcn_mfma_f32_16x16x32_f16(a, bh[j], acc[j], 0, 0, 0);
    }

    // stash partials: red[wave][j*256 + r*64 + lane]  (stride-1 per wave: no conflicts)
    __shared__ float red[4][JT * 256];
#pragma unroll
    for (int j = 0; j < JT; ++j)
#pragma unroll
        for (int r = 0; r < 4; ++r)
            red[wave][j * 256 + r * 64 + lane] = acc[j][r];
    __syncthreads();

    // reduce + epilogue: thread t handles flat idx k*256+t for k in [0,JT)
    // mapping: j = k, r = t>>6, l = t&63 -> row = row0+(l>>4)*4+r, col = col0+k*16+(l&15)
    int r = tid >> 6, l = tid & 63;
    int row = row0 + (l >> 4) * 4 + r;
    if (row >= N) return;
    unsigned mk = masks[row];
#pragma unroll
    for (int k = 0; k < JT; ++k) {
        float v = red[0][k * 256 + tid] + red[1][k * 256 + tid] +
                  red[2][k * 256 + tid] + red[3][k * 256 + tid];
        int cc = col0 + k * 16 + (l & 15);
        v = selu_f(v + bias[cc]);
        if (cc < 2) {
            if (cc == 0) { if (mk & 2u) v = 0.f; else if (mk & 1u) v = 1.f; }
            else         { if (mk & 8u) v = 1.f; else if (mk & 4u) v = 0.f; }
        }
        O16[(size_t)row * M + cc] = __float2half(v);
    }
}

// ---------------- final layer (C=2): out = bfix(x + selu(g @ W5s + b5)) -----
__global__ __launch_bounds__(256) void final5_kernel(const __half* __restrict__ g,
                                                     const float* __restrict__ W5,
                                                     const float* __restrict__ b5,
                                                     const unsigned* __restrict__ masks,
                                                     const float* __restrict__ x,
                                                     float* __restrict__ out,
                                                     int N, int KA) {
    int wave = threadIdx.x >> 6, lane = threadIdx.x & 63;
    int n = blockIdx.x * 4 + wave;
    if (n >= N) return;
    float a0 = 0.f, a1 = 0.f;
    const __half* gp = g + (size_t)n * KA;
    for (int k = lane * 2; k < KA; k += 128) {
        float2 f = __half22float2(*(const __half2*)(gp + k));
        float4 w = *(const float4*)(W5 + (size_t)k * 2);
        a0 += f.x * w.x + f.y * w.z;
        a1 += f.x * w.y + f.y * w.w;
    }
#pragma unroll
    for (int off = 32; off >= 1; off >>= 1) {
        a0 += __shfl_xor(a0, off);
        a1 += __shfl_xor(a1, off);
    }
    if (lane == 0) {
        unsigned mk = masks[n];
        float v0 = x[n * 10 + 0] + selu_f(a0 + b5[0]);
        float v1 = x[n * 10 + 1] + selu_f(a1 + b5[1]);
        if (mk & 2u) v0 = 0.f; else if (mk & 1u) v0 = 1.f;
        if (mk & 8u) v1 = 1.f; else if (mk & 4u) v1 = 0.f;
        out[n * 2 + 0] = v0;
        out[n * 2 + 1] = v1;
    }
}

// ---------------------------------------------------------------------------
extern "C" void kernel_launch(void* const* d_in, const int* in_sizes, int n_in,
                              void* d_out, int out_size, void* d_ws, size_t ws_size,
                              hipStream_t stream) {
    const float* x   = (const float*)d_in[0];
    const int*   ei  = (const int*)d_in[1];
    const float* cf  = (const float*)d_in[2];
    const float* cw[4] = {(const float*)d_in[3], (const float*)d_in[5],
                          (const float*)d_in[7], (const float*)d_in[9]};
    const float* cb[4] = {(const float*)d_in[4], (const float*)d_in[6],
                          (const float*)d_in[8], (const float*)d_in[10]};
    const float* gw[5], *gas[5], *gad[5], *gb[5];
    for (int i = 0; i < 5; ++i) {
        gw[i]  = (const float*)d_in[11 + 4 * i];
        gas[i] = (const float*)d_in[12 + 4 * i];
        gad[i] = (const float*)d_in[13 + 4 * i];
        gb[i]  = (const float*)d_in[14 + 4 * i];
    }
    const int N = in_sizes[0] / 10;        // 10000
    const int E = in_sizes[1] / 2;         // 160000
    const int EN = E + N;
    const int NB = (N + 255) / 256;        // scan blocks (40)

    // ---- workspace carve-up ----
    char* base = (char*)d_ws;
    size_t off = 0;
    auto alloc = [&](size_t bytes) -> char* {
        char* p = base + off;
        off = (off + bytes + 255) & ~(size_t)255;
        return p;
    };
    float* cfp   = (float*)alloc((size_t)4 * PSZ * 4);
    float* c1p   = (float*)alloc((size_t)16 * PSZ * 4);
    float* c2p   = (float*)alloc((size_t)32 * PSZ * 4);
    float* c3p   = (float*)alloc((size_t)64 * PSZ * 4);
    float* c4p   = (float*)alloc((size_t)24 * PSZ * 4);
    float* gfeat = (float*)alloc(24 * 4);
    __half* hA16 = (__half*)alloc((size_t)N * 256 * 2);
    __half* hB16 = (__half*)alloc((size_t)N * 256 * 2);
    __half* g    = (__half*)alloc((size_t)N * 2048 * 2);
    float* esed  = (float*)alloc((size_t)N * 32 * 4);
    float* zinv  = (float*)alloc((size_t)N * 16 * 4);
    float* palpha = (float*)alloc((size_t)EN * 16 * 4);      // fp32 numerators
    float* wesed = (float*)alloc((size_t)13056 * 4);         // all 5 layers
    float* wstack= (float*)alloc((size_t)2048 * 2 * 4);
    unsigned short* bt = (unsigned short*)alloc((size_t)679936 * 2);  // all 4 GEMM layers
    unsigned* masks = (unsigned*)alloc((size_t)N * 4);
    int* cnt    = (int*)alloc((size_t)N * 4);
    int* pref   = (int*)alloc((size_t)N * 4);
    int* bsums  = (int*)alloc(64 * 4);
    int* indptr = (int*)alloc((size_t)(N + 1) * 4);
    int* cursor = (int*)alloc((size_t)N * 4);
    int* col    = (int*)alloc((size_t)EN * 4);
    (void)ws_size; // ~78 MB

    // ---- one-shot fused weight prep (all 5 layers) ----
    prep_all<<<235, 256, 0, stream>>>(gw[0], gw[1], gw[2], gw[3], gw[4],
                                      gas[0], gas[1], gas[2], gas[3], gas[4],
                                      gad[0], gad[1], gad[2], gad[3], gad[4],
                                      bt, wesed, wstack);

    // ---- CNN (padded layout; single memset zeroes all borders) ----
    hipMemsetAsync(cfp, 0, (size_t)140 * PSZ * 4, stream);
    pad_input<<<(4 * 4096 + 255) / 256, 256, 0, stream>>>(cf, cfp);
    conv3x3_pad<4><<<dim3(16, 16), 256, 0, stream>>>(cfp, cw[0], cb[0], c1p);
    conv3x3_pad<16><<<dim3(16, 32), 256, 0, stream>>>(c1p, cw[1], cb[1], c2p);
    conv3x3_pad<32><<<dim3(16, 64), 256, 0, stream>>>(c2p, cw[2], cb[2], c3p);
    conv3x3_pad<64><<<dim3(16, 24), 256, 0, stream>>>(c3p, cw[3], cb[3], c4p);
    avgpool_c<<<24, 256, 0, stream>>>(c4p, gfeat);

    // ---- h0 (padded to 48, fp16) + masks ----
    build_h0<<<(N + 255) / 256, 256, 0, stream>>>(x, gfeat, hA16, masks, N);

    // ---- CSR by dst (incl self loops), parallel scan ----
    hipMemsetAsync(cnt, 0, (size_t)N * 4, stream);
    count_dst<<<(EN + 255) / 256, 256, 0, stream>>>(ei, cnt, E, N);
    scan_blocks<<<NB, 256, 0, stream>>>(cnt, pref, bsums, N);
    scan_sums<<<1, 64, 0, stream>>>(bsums, NB);
    scan_apply<<<NB, 256, 0, stream>>>(pref, bsums, indptr, cursor, N, EN);
    scatter_edges<<<(EN + 255) / 256, 256, 0, stream>>>(ei, cursor, col, E, N);

    // ---- GAT layers ----
    const int Kp[5] = {48, 64, 128, 256, 128};   // padded input dims
    const int Hs[5] = {8, 16, 8, 8, 16};
    const int Cs[5] = {64, 128, 256, 128, 2};
    const int btOffA[5] = {0, 24576, 155648, 417792, 0};
    const int weOffA[5] = {0, 768, 2816, 4864, 8960};

    const __half* hin16 = hA16;
    __half* hout16[4]  = {hB16, hA16, hB16, hA16};

    for (int lyr = 0; lyr < 5; ++lyr) {
        int KP = Kp[lyr], H = Hs[lyr], C = Cs[lyr];
        int KA = H * KP;
        esed_kernel<<<(N * 2 * H + 255) / 256, 256, 0, stream>>>(hin16, wesed + weOffA[lyr],
                                                                 esed, N, KP, 2 * H);
        attn_kernel<<<(N * H + 255) / 256, 256, 0, stream>>>(esed, indptr, col,
                                                             palpha, zinv, N, H);
        if (lyr == 0)
            gat_gather<8, 48, 10><<<(N + 9) / 10, 240, 0, stream>>>(hin16, palpha, zinv, indptr, col, g, N);
        else if (lyr == 1)
            gat_gather<16, 64, 8><<<(N + 7) / 8, 256, 0, stream>>>(hin16, palpha, zinv, indptr, col, g, N);
        else if (lyr == 2)
            gat_gather<8, 128, 4><<<(N + 3) / 4, 256, 0, stream>>>(hin16, palpha, zinv, indptr, col, g, N);
        else if (lyr == 3)
            gat_gather<8, 256, 2><<<(N + 1) / 2, 256, 0, stream>>>(hin16, palpha, zinv, indptr, col, g, N);
        else
            gat_gather<16, 128, 4><<<(N + 3) / 4, 256, 0, stream>>>(hin16, palpha, zinv, indptr, col, g, N);

        if (lyr < 4) {
            const unsigned short* btL = bt + btOffA[lyr];
            int gx = (N + 15) / 16;
            // grid = (N/16, C/64); 4 waves/block split K in-block
            gemm_kr<4><<<dim3(gx, C / 64), 256, 0, stream>>>(g, btL, gb[lyr], masks,
                                                             hout16[lyr], N, KA, C);
            hin16 = hout16[lyr];
        } else {
            final5_kernel<<<(N + 3) / 4, 256, 0, stream>>>(g, wstack, gb[4], masks, x,
                                                           (float*)d_out, N, KA);
        }
    }
}

// Round 4
// 552.480 us; speedup vs baseline: 1.1592x; 1.1156x over previous
//
#include <hip/hip_runtime.h>
#include <hip/hip_fp16.h>
#include <math.h>

// ---------------------------------------------------------------------------
// NetGlobGATFix. R20: LDS-staged GEMM (m97-lite) replaces direct-global MFMA.
//   - R19's gemm_kr: fragment loads straight from global = 16 scattered lines
//     per load, vmcnt(0) per K-iter -> latency-bound, 50.5us on layer 3
//     (MfmaUtil 3.6%, 957 GB/s on a 42 MB stream).
//   - gemm_lds: 64x64 tile/block, BK=64, reg-staged padded LDS (LDP=72,
//     ~2-way aliasing = free), next-tile global prefetch into regs overlaps
//     compute, 10 ds_read_b128 + 8 MFMA per wave per step. A coalesced,
//     read once per col-block; B L2-resident. Grid (ceil(N/64), C/64).
//   - Everything else identical to R19 (616us).
// ---------------------------------------------------------------------------

#define DEVFN static __device__ __forceinline__

typedef __attribute__((ext_vector_type(8))) _Float16 half8;
typedef __attribute__((ext_vector_type(4))) float f32x4;

DEVFN float selu_f(float v) {
    const float scale = 1.0507009873554805f;
    const float alpha = 1.6732632423543772f;
    return v > 0.f ? scale * v : scale * alpha * (expf(v) - 1.f);
}

DEVFN float lrelu02(float v) { return v > 0.f ? v : 0.2f * v; }

// ---------------- CNN (padded 66x66 layout) ----------------
#define PST 66
#define PSZ (66 * 66)

__global__ void pad_input(const float* __restrict__ cf, float* __restrict__ out) {
    int t = blockIdx.x * blockDim.x + threadIdx.x;
    if (t >= 4 * 4096) return;
    int c = t >> 12, pix = t & 4095;
    int y = pix >> 6, x = pix & 63;
    out[c * PSZ + (y + 1) * PST + (x + 1)] = cf[t];
}

template <int CIN>
__global__ __launch_bounds__(256) void conv3x3_pad(const float* __restrict__ in,
                                                   const float* __restrict__ w,
                                                   const float* __restrict__ b,
                                                   float* __restrict__ out) {
    int x  = threadIdx.x & 63;
    int yg = threadIdx.x >> 6;
    int y  = blockIdx.x * 4 + yg;          // 0..63
    int co = blockIdx.y;
    float acc = b[co];
    const float* wp = w + (size_t)co * CIN * 9;
#pragma unroll 4
    for (int ci = 0; ci < CIN; ++ci) {
        const float* ip = in + ci * PSZ + y * PST + x;
        const float* wr = wp + ci * 9;
        acc += wr[0] * ip[0]           + wr[1] * ip[1]           + wr[2] * ip[2]
             + wr[3] * ip[PST]         + wr[4] * ip[PST + 1]     + wr[5] * ip[PST + 2]
             + wr[6] * ip[2 * PST]     + wr[7] * ip[2 * PST + 1] + wr[8] * ip[2 * PST + 2];
    }
    out[(size_t)co * PSZ + (y + 1) * PST + (x + 1)] = selu_f(acc);
}

__global__ void avgpool_c(const float* __restrict__ in, float* __restrict__ gfeat) {
    int c = blockIdx.x;            // 24 blocks
    int t = threadIdx.x;           // 256 threads
    float s = 0.f;
    for (int i = t; i < 4096; i += 256) {
        int y = i >> 6, x = i & 63;
        s += in[c * PSZ + (y + 1) * PST + (x + 1)];
    }
#pragma unroll
    for (int off = 32; off >= 1; off >>= 1) s += __shfl_xor(s, off);
    __shared__ float red[4];
    int wave = t >> 6, lane = t & 63;
    if (lane == 0) red[wave] = s;
    __syncthreads();
    if (t == 0) gfeat[c] = (red[0] + red[1] + red[2] + red[3]) * (1.f / 4096.f);
}

// ---------------- node feature init (padded to 48 ch, fp16) + masks ---------
__global__ void build_h0(const float* __restrict__ x, const float* __restrict__ gfeat,
                         __half* __restrict__ h0f, unsigned* __restrict__ masks, int N) {
    int n = blockIdx.x * blockDim.x + threadIdx.x;
    if (n >= N) return;
    float x0 = x[n * 10 + 0], x1 = x[n * 10 + 1];
    unsigned mk = (x0 == 1.f ? 1u : 0u) | (x0 == 0.f ? 2u : 0u) |
                  (x1 == 0.f ? 4u : 0u) | (x1 == 1.f ? 8u : 0u);
    masks[n] = mk;
    __half* hq = h0f + (size_t)n * 48;
#pragma unroll
    for (int j = 0; j < 48; ++j) {
        float v = (j < 24) ? gfeat[j] : (j < 34 ? x[n * 10 + (j - 24)] : 0.f);
        hq[j] = __float2half(v);
    }
}

// ---------------- CSR build (parallel scan) ----------------
__global__ void count_dst(const int* __restrict__ ei, int* __restrict__ cnt, int E, int N) {
    int t = blockIdx.x * blockDim.x + threadIdx.x;
    if (t >= E + N) return;
    int dst = (t < E) ? ei[E + t] : (t - E);
    atomicAdd(&cnt[dst], 1);
}

__global__ void scan_blocks(const int* __restrict__ cnt, int* __restrict__ pref,
                            int* __restrict__ bsums, int n) {
    __shared__ int sdata[256];
    int i = blockIdx.x * 256 + threadIdx.x;
    int v = (i < n) ? cnt[i] : 0;
    sdata[threadIdx.x] = v;
    __syncthreads();
    for (int off = 1; off < 256; off <<= 1) {
        int tmp = (threadIdx.x >= off) ? sdata[threadIdx.x - off] : 0;
        __syncthreads();
        sdata[threadIdx.x] += tmp;
        __syncthreads();
    }
    if (i < n) pref[i] = sdata[threadIdx.x] - v;
    if (threadIdx.x == 255) bsums[blockIdx.x] = sdata[255];
}

__global__ void scan_sums(int* __restrict__ bsums, int nb) {
    int tid = threadIdx.x;                 // 64
    int orig = (tid < nb) ? bsums[tid] : 0;
    int v = orig;
#pragma unroll
    for (int off = 1; off < 64; off <<= 1) {
        int u = __shfl_up(v, off);
        if (tid >= off) v += u;
    }
    if (tid < nb) bsums[tid] = v - orig;
}

__global__ void scan_apply(const int* __restrict__ pref, const int* __restrict__ bsums,
                           int* __restrict__ indptr, int* __restrict__ cursor,
                           int n, int total) {
    int i = blockIdx.x * 256 + threadIdx.x;
    if (i == 0) indptr[n] = total;
    if (i >= n) return;
    int e = bsums[blockIdx.x] + pref[i];
    indptr[i] = e;
    cursor[i] = e;
}

__global__ void scatter_edges(const int* __restrict__ ei, int* __restrict__ cursor,
                              int* __restrict__ col, int E, int N) {
    int t = blockIdx.x * blockDim.x + threadIdx.x;
    if (t >= E + N) return;
    int src, dst;
    if (t < E) { src = ei[t]; dst = ei[E + t]; }
    else       { src = dst = t - E; }
    int pos = atomicAdd(&cursor[dst], 1);
    col[pos] = src;
}

// ---------------- fused one-shot weight prep --------------------------------
// bt layout per layer: bt[btOff + m*KA + h*Kp + k] = fp16(W[k*HC + h*C + m])
// wesed[weOff + k*2H + o] = sum_c W[k,h*C+c]*a[h,c]  (h=o%H, a=as/ad by o<H).
// wstack (layer 4, C=2): wstack[(h*Kp+k)*2+c] = W4[k*32 + h*2 + c].
__global__ __launch_bounds__(256) void prep_all(
        const float* __restrict__ W0, const float* __restrict__ W1,
        const float* __restrict__ W2, const float* __restrict__ W3,
        const float* __restrict__ W4,
        const float* __restrict__ as0, const float* __restrict__ as1,
        const float* __restrict__ as2, const float* __restrict__ as3,
        const float* __restrict__ as4,
        const float* __restrict__ ad0, const float* __restrict__ ad1,
        const float* __restrict__ ad2, const float* __restrict__ ad3,
        const float* __restrict__ ad4,
        unsigned short* __restrict__ bt, float* __restrict__ wesed,
        float* __restrict__ wstack) {
    const int Kc[5]  = {34, 64, 128, 256, 128};
    const int Kpc[5] = {48, 64, 128, 256, 128};
    const int Hc[5]  = {8, 16, 8, 8, 16};
    const int Cc[5]  = {64, 128, 256, 128, 2};
    const int HCc[5] = {512, 2048, 2048, 1024, 32};
    const int KAc[5] = {384, 1024, 1024, 2048, 2048};
    const int btOff[5] = {0, 24576, 155648, 417792, 679936};
    const int weOff[5] = {0, 768, 2816, 4864, 8960};

    int b = blockIdx.x, tid = threadIdx.x;

    if (b < 168) {
        // ---- LDS-tiled transpose, one (layer, head, 64x64 tile) per block --
        int lyr, tloc;
        if (b < 8)        { lyr = 0; tloc = b; }
        else if (b < 40)  { lyr = 1; tloc = b - 8; }
        else if (b < 104) { lyr = 2; tloc = b - 40; }
        else              { lyr = 3; tloc = b - 104; }
        const int ktl[4] = {1, 1, 2, 4};   // ceil(Kp/64)
        const int mtl[4] = {1, 2, 4, 2};   // ceil(C/64)
        int kt = ktl[lyr], mt = mtl[lyr];
        int per_h = kt * mt;
        int h = tloc / per_h, r = tloc - h * per_h;
        int ki = r % kt, mi = r / kt;
        int k0 = ki * 64, m0 = mi * 64;
        int K = Kc[lyr], Kp = Kpc[lyr], C = Cc[lyr], HC = HCc[lyr], KA = KAc[lyr];
        const float* W;
        if (lyr == 0) W = W0; else if (lyr == 1) W = W1;
        else if (lyr == 2) W = W2; else W = W3;

        __shared__ float tile[64][65];
        int c = tid & 63, rg = tid >> 6;
        for (int r2 = rg; r2 < 64; r2 += 4) {       // coalesced 256B reads
            int k = k0 + r2, m = m0 + c;
            float v = (k < K && m < C) ? W[(size_t)k * HC + h * C + m] : 0.f;
            tile[r2][c] = v;
        }
        __syncthreads();
        unsigned short* bp = bt + btOff[lyr];
        for (int mr = rg; mr < 64; mr += 4) {       // coalesced 128B fp16 writes
            int m = m0 + mr, k = k0 + c;
            if (m < C && k < Kp)
                bp[(size_t)m * KA + h * Kp + k] =
                    __half_as_ushort(__float2half(tile[c][mr]));
        }
    } else if (b < 184) {
        // ---- wstack for layer 4 (C=2): 4096 outputs ----
        int u = (b - 168) * 256 + tid;              // Kp=128, H=16, HC=32
        int cc = u & 1, rr = u >> 1;
        int h = rr >> 7, k = rr & 127;
        wstack[u] = W4[k * 32 + h * 2 + cc];
    } else {
        // ---- wesed dots: sizes {768,2048,2048,4096,4096} -> 51 blocks ----
        int wb = b - 184;
        int lyr, u0;
        if (wb < 3)       { lyr = 0; u0 = wb * 256; }
        else if (wb < 11) { lyr = 1; u0 = (wb - 3) * 256; }
        else if (wb < 19) { lyr = 2; u0 = (wb - 11) * 256; }
        else if (wb < 35) { lyr = 3; u0 = (wb - 19) * 256; }
        else              { lyr = 4; u0 = (wb - 35) * 256; }
        int u = u0 + tid;
        int K = Kc[lyr], Kp = Kpc[lyr], H = Hc[lyr], C = Cc[lyr], HC = HCc[lyr];
        int H2 = 2 * H;
        if (u < Kp * H2) {
            int k = u / H2, o = u - k * H2;
            float s = 0.f;
            if (k < K) {
                int h = (o < H) ? o : o - H;
                const float *W, *as_, *ad_;
                if (lyr == 0)      { W = W0; as_ = as0; ad_ = ad0; }
                else if (lyr == 1) { W = W1; as_ = as1; ad_ = ad1; }
                else if (lyr == 2) { W = W2; as_ = as2; ad_ = ad2; }
                else if (lyr == 3) { W = W3; as_ = as3; ad_ = ad3; }
                else               { W = W4; as_ = as4; ad_ = ad4; }
                const float* av = ((o < H) ? as_ : ad_) + h * C;
                const float* wp = W + (size_t)k * HC + h * C;
#pragma unroll 4
                for (int c2 = 0; c2 < C; ++c2) s += wp[c2] * av[c2];
            }
            wesed[weOff[lyr] + u] = s;
        }
    }
}

// ---------------- es/ed: esed[n, o] = hin16[n,:] @ wesed[:,o], o < 2H -------
__global__ void esed_kernel(const __half* __restrict__ hin, const float* __restrict__ wesed,
                            float* __restrict__ esed, int N, int Kp, int H2) {
    int t = blockIdx.x * blockDim.x + threadIdx.x;
    if (t >= N * H2) return;
    int n = t / H2, o = t - n * H2;
    const __half2* hp = (const __half2*)(hin + (size_t)n * Kp);
    float s = 0.f;
    for (int k2 = 0; k2 < Kp / 2; ++k2) {
        float2 f = __half22float2(hp[k2]);
        s += f.x * wesed[(2 * k2) * H2 + o] + f.y * wesed[(2 * k2 + 1) * H2 + o];
    }
    esed[t] = s;
}

// -------- attention: single pass, 4-deep gather pipeline --------------------
__global__ void attn_kernel(const float* __restrict__ esed,
                            const int* __restrict__ indptr, const int* __restrict__ col,
                            float* __restrict__ palpha, float* __restrict__ zinv,
                            int N, int H) {
    int t = blockIdx.x * blockDim.x + threadIdx.x;
    if (t >= N * H) return;
    int n = t / H, h = t - n * H;
    int H2 = 2 * H;
    float edv = esed[n * H2 + H + h];
    int beg = indptr[n], end = indptr[n + 1];
    float z = 0.f;
    int i = beg;
    for (; i + 3 < end; i += 4) {
        int s0 = col[i], s1 = col[i + 1], s2 = col[i + 2], s3 = col[i + 3];
        float e0 = esed[s0 * H2 + h];
        float e1 = esed[s1 * H2 + h];
        float e2 = esed[s2 * H2 + h];
        float e3 = esed[s3 * H2 + h];
        float p0 = expf(lrelu02(e0 + edv));
        float p1 = expf(lrelu02(e1 + edv));
        float p2 = expf(lrelu02(e2 + edv));
        float p3 = expf(lrelu02(e3 + edv));
        palpha[(size_t)(i + 0) * H + h] = p0;
        palpha[(size_t)(i + 1) * H + h] = p1;
        palpha[(size_t)(i + 2) * H + h] = p2;
        palpha[(size_t)(i + 3) * H + h] = p3;
        z += p0; z += p1; z += p2; z += p3;
    }
    for (; i < end; ++i) {
        float e = lrelu02(esed[col[i] * H2 + h] + edv);
        float p = expf(e);
        palpha[(size_t)i * H + h] = p;
        z += p;
    }
    zinv[t] = (1.f / H) / (z + 1e-16f);
}

// -------- gather: 4-deep hin pipeline ---------------------------------------
template <int H, int KP, int NPB>
__global__ __launch_bounds__(NPB * KP / 2) void gat_gather(
        const __half* __restrict__ hinf, const float* __restrict__ palpha,
        const float* __restrict__ zinv, const int* __restrict__ indptr,
        const int* __restrict__ col, __half* __restrict__ g, int N) {
    const int TPN = KP / 2;
    int sub = threadIdx.x / TPN;
    int j   = threadIdx.x % TPN;
    int n = blockIdx.x * NPB + sub;
    if (n >= N) return;
    int c0 = j * 2;
    float acc[H][2];
#pragma unroll
    for (int h = 0; h < H; ++h) { acc[h][0] = 0.f; acc[h][1] = 0.f; }
    int beg = indptr[n], end = indptr[n + 1];
    int i = beg;
    for (; i + 3 < end; i += 4) {
        int s0 = col[i], s1 = col[i + 1], s2 = col[i + 2], s3 = col[i + 3];
        __half2 hv0 = *(const __half2*)(hinf + (size_t)s0 * KP + c0);
        __half2 hv1 = *(const __half2*)(hinf + (size_t)s1 * KP + c0);
        __half2 hv2 = *(const __half2*)(hinf + (size_t)s2 * KP + c0);
        __half2 hv3 = *(const __half2*)(hinf + (size_t)s3 * KP + c0);
        float2 fv[4] = {__half22float2(hv0), __half22float2(hv1),
                        __half22float2(hv2), __half22float2(hv3)};
#pragma unroll
        for (int e = 0; e < 4; ++e) {
            const float2* ap = (const float2*)(palpha + (size_t)(i + e) * H);
            float2 f = fv[e];
#pragma unroll
            for (int h2 = 0; h2 < H / 2; ++h2) {
                float2 aa = ap[h2];
                acc[2 * h2 + 0][0] += aa.x * f.x;
                acc[2 * h2 + 0][1] += aa.x * f.y;
                acc[2 * h2 + 1][0] += aa.y * f.x;
                acc[2 * h2 + 1][1] += aa.y * f.y;
            }
        }
    }
    for (; i < end; ++i) {
        int src = col[i];
        __half2 hv = *(const __half2*)(hinf + (size_t)src * KP + c0);
        float2 f = __half22float2(hv);
        const float2* ap = (const float2*)(palpha + (size_t)i * H);
#pragma unroll
        for (int h2 = 0; h2 < H / 2; ++h2) {
            float2 aa = ap[h2];
            acc[2 * h2 + 0][0] += aa.x * f.x;
            acc[2 * h2 + 0][1] += aa.x * f.y;
            acc[2 * h2 + 1][0] += aa.y * f.x;
            acc[2 * h2 + 1][1] += aa.y * f.y;
        }
    }
    __half* gp = g + (size_t)n * (H * KP) + c0;
#pragma unroll
    for (int h = 0; h < H; ++h) {
        float zf = zinv[n * H + h];
        *(__half2*)(gp + h * KP) = __floats2half2_rn(acc[h][0] * zf, acc[h][1] * zf);
    }
}

// ---------------- LDS-staged f16 MFMA GEMM (64x64 tile, BK=64) --------------
// 256 threads = 4 waves; wave w computes rows [16w,16w+16) x 64 cols.
// Reg-staged padded LDS (LDP=72 halves) -> ~2-way bank aliasing (free).
// Next-tile global prefetch into regs overlaps compute. 2 barriers/K-step.
// Grid = (ceil(N/64), M/64). A coalesced (8 lanes x 128B rows), B L2-resident.
#define LDP 72
__global__ __launch_bounds__(256) void gemm_lds(const __half* __restrict__ A,
                                                const unsigned short* __restrict__ Bhi,
                                                const float* __restrict__ bias,
                                                const unsigned* __restrict__ masks,
                                                __half* __restrict__ O16,
                                                int N, int K, int M) {
    __shared__ __half lA[64 * LDP], lB[64 * LDP];
    int tid = threadIdx.x;
    int wave = tid >> 6, lane = tid & 63;
    int ln16 = lane & 15, q = lane >> 4;
    int row0 = blockIdx.x * 64;
    int col0 = blockIdx.y * 64;

    // staging coords: thread t loads 16B chunks for rows r0=t/8 and r1=r0+32
    int r0 = tid >> 3, r1 = r0 + 32;
    int ac = (tid & 7) * 8;                      // col offset in halves
    int ga0 = min(row0 + r0, N - 1);             // clamp tail rows (safe dup)
    int ga1 = min(row0 + r1, N - 1);
    const __half* Bp = (const __half*)Bhi;
    const __half* a0p = A + (size_t)ga0 * K + ac;
    const __half* a1p = A + (size_t)ga1 * K + ac;
    const __half* b0p = Bp + (size_t)(col0 + r0) * K + ac;
    const __half* b1p = Bp + (size_t)(col0 + r1) * K + ac;

    half8 ra0 = *(const half8*)(a0p);
    half8 ra1 = *(const half8*)(a1p);
    half8 rb0 = *(const half8*)(b0p);
    half8 rb1 = *(const half8*)(b1p);

    f32x4 acc[4];
#pragma unroll
    for (int j = 0; j < 4; ++j) acc[j] = (f32x4){0.f, 0.f, 0.f, 0.f};

    for (int kc = 0; kc < K; kc += 64) {
        __syncthreads();                         // prev compute done, LDS free
        *(half8*)(lA + r0 * LDP + ac) = ra0;
        *(half8*)(lA + r1 * LDP + ac) = ra1;
        *(half8*)(lB + r0 * LDP + ac) = rb0;
        *(half8*)(lB + r1 * LDP + ac) = rb1;
        __syncthreads();
        int kn = kc + 64;
        if (kn < K) {                            // prefetch next tile -> regs
            ra0 = *(const half8*)(a0p + kn);
            ra1 = *(const half8*)(a1p + kn);
            rb0 = *(const half8*)(b0p + kn);
            rb1 = *(const half8*)(b1p + kn);
        }
#pragma unroll
        for (int kk = 0; kk < 2; ++kk) {
            half8 af = *(const half8*)(lA + (wave * 16 + ln16) * LDP + kk * 32 + q * 8);
#pragma unroll
            for (int j = 0; j < 4; ++j) {
                half8 bf = *(const half8*)(lB + (j * 16 + ln16) * LDP + kk * 32 + q * 8);
                acc[j] = __builtin_amdgcn_mfma_f32_16x16x32_f16(af, bf, acc[j], 0, 0, 0);
            }
        }
    }

    // epilogue: col = lane&15, row = wave*16 + (lane>>4)*4 + reg
#pragma unroll
    for (int j = 0; j < 4; ++j) {
        int cc = col0 + j * 16 + ln16;
        float bv = bias[cc];
#pragma unroll
        for (int r = 0; r < 4; ++r) {
            int rr = row0 + wave * 16 + q * 4 + r;
            if (rr >= N) continue;
            float v = selu_f(acc[j][r] + bv);
            if (cc < 2) {
                unsigned mk = masks[rr];
                if (cc == 0) { if (mk & 2u) v = 0.f; else if (mk & 1u) v = 1.f; }
                else         { if (mk & 8u) v = 1.f; else if (mk & 4u) v = 0.f; }
            }
            O16[(size_t)rr * M + cc] = __float2half(v);
        }
    }
}

// ---------------- final layer (C=2): out = bfix(x + selu(g @ W5s + b5)) -----
__global__ __launch_bounds__(256) void final5_kernel(const __half* __restrict__ g,
                                                     const float* __restrict__ W5,
                                                     const float* __restrict__ b5,
                                                     const unsigned* __restrict__ masks,
                                                     const float* __restrict__ x,
                                                     float* __restrict__ out,
                                                     int N, int KA) {
    int wave = threadIdx.x >> 6, lane = threadIdx.x & 63;
    int n = blockIdx.x * 4 + wave;
    if (n >= N) return;
    float a0 = 0.f, a1 = 0.f;
    const __half* gp = g + (size_t)n * KA;
    for (int k = lane * 2; k < KA; k += 128) {
        float2 f = __half22float2(*(const __half2*)(gp + k));
        float4 w = *(const float4*)(W5 + (size_t)k * 2);
        a0 += f.x * w.x + f.y * w.z;
        a1 += f.x * w.y + f.y * w.w;
    }
#pragma unroll
    for (int off = 32; off >= 1; off >>= 1) {
        a0 += __shfl_xor(a0, off);
        a1 += __shfl_xor(a1, off);
    }
    if (lane == 0) {
        unsigned mk = masks[n];
        float v0 = x[n * 10 + 0] + selu_f(a0 + b5[0]);
        float v1 = x[n * 10 + 1] + selu_f(a1 + b5[1]);
        if (mk & 2u) v0 = 0.f; else if (mk & 1u) v0 = 1.f;
        if (mk & 8u) v1 = 1.f; else if (mk & 4u) v1 = 0.f;
        out[n * 2 + 0] = v0;
        out[n * 2 + 1] = v1;
    }
}

// ---------------------------------------------------------------------------
extern "C" void kernel_launch(void* const* d_in, const int* in_sizes, int n_in,
                              void* d_out, int out_size, void* d_ws, size_t ws_size,
                              hipStream_t stream) {
    const float* x   = (const float*)d_in[0];
    const int*   ei  = (const int*)d_in[1];
    const float* cf  = (const float*)d_in[2];
    const float* cw[4] = {(const float*)d_in[3], (const float*)d_in[5],
                          (const float*)d_in[7], (const float*)d_in[9]};
    const float* cb[4] = {(const float*)d_in[4], (const float*)d_in[6],
                          (const float*)d_in[8], (const float*)d_in[10]};
    const float* gw[5], *gas[5], *gad[5], *gb[5];
    for (int i = 0; i < 5; ++i) {
        gw[i]  = (const float*)d_in[11 + 4 * i];
        gas[i] = (const float*)d_in[12 + 4 * i];
        gad[i] = (const float*)d_in[13 + 4 * i];
        gb[i]  = (const float*)d_in[14 + 4 * i];
    }
    const int N = in_sizes[0] / 10;        // 10000
    const int E = in_sizes[1] / 2;         // 160000
    const int EN = E + N;
    const int NB = (N + 255) / 256;        // scan blocks (40)

    // ---- workspace carve-up ----
    char* base = (char*)d_ws;
    size_t off = 0;
    auto alloc = [&](size_t bytes) -> char* {
        char* p = base + off;
        off = (off + bytes + 255) & ~(size_t)255;
        return p;
    };
    float* cfp   = (float*)alloc((size_t)4 * PSZ * 4);
    float* c1p   = (float*)alloc((size_t)16 * PSZ * 4);
    float* c2p   = (float*)alloc((size_t)32 * PSZ * 4);
    float* c3p   = (float*)alloc((size_t)64 * PSZ * 4);
    float* c4p   = (float*)alloc((size_t)24 * PSZ * 4);
    float* gfeat = (float*)alloc(24 * 4);
    __half* hA16 = (__half*)alloc((size_t)N * 256 * 2);
    __half* hB16 = (__half*)alloc((size_t)N * 256 * 2);
    __half* g    = (__half*)alloc((size_t)N * 2048 * 2);
    float* esed  = (float*)alloc((size_t)N * 32 * 4);
    float* zinv  = (float*)alloc((size_t)N * 16 * 4);
    float* palpha = (float*)alloc((size_t)EN * 16 * 4);      // fp32 numerators
    float* wesed = (float*)alloc((size_t)13056 * 4);         // all 5 layers
    float* wstack= (float*)alloc((size_t)2048 * 2 * 4);
    unsigned short* bt = (unsigned short*)alloc((size_t)679936 * 2);  // all 4 GEMM layers
    unsigned* masks = (unsigned*)alloc((size_t)N * 4);
    int* cnt    = (int*)alloc((size_t)N * 4);
    int* pref   = (int*)alloc((size_t)N * 4);
    int* bsums  = (int*)alloc(64 * 4);
    int* indptr = (int*)alloc((size_t)(N + 1) * 4);
    int* cursor = (int*)alloc((size_t)N * 4);
    int* col    = (int*)alloc((size_t)EN * 4);
    (void)ws_size; // ~78 MB

    // ---- one-shot fused weight prep (all 5 layers) ----
    prep_all<<<235, 256, 0, stream>>>(gw[0], gw[1], gw[2], gw[3], gw[4],
                                      gas[0], gas[1], gas[2], gas[3], gas[4],
                                      gad[0], gad[1], gad[2], gad[3], gad[4],
                                      bt, wesed, wstack);

    // ---- CNN (padded layout; single memset zeroes all borders) ----
    hipMemsetAsync(cfp, 0, (size_t)140 * PSZ * 4, stream);
    pad_input<<<(4 * 4096 + 255) / 256, 256, 0, stream>>>(cf, cfp);
    conv3x3_pad<4><<<dim3(16, 16), 256, 0, stream>>>(cfp, cw[0], cb[0], c1p);
    conv3x3_pad<16><<<dim3(16, 32), 256, 0, stream>>>(c1p, cw[1], cb[1], c2p);
    conv3x3_pad<32><<<dim3(16, 64), 256, 0, stream>>>(c2p, cw[2], cb[2], c3p);
    conv3x3_pad<64><<<dim3(16, 24), 256, 0, stream>>>(c3p, cw[3], cb[3], c4p);
    avgpool_c<<<24, 256, 0, stream>>>(c4p, gfeat);

    // ---- h0 (padded to 48, fp16) + masks ----
    build_h0<<<(N + 255) / 256, 256, 0, stream>>>(x, gfeat, hA16, masks, N);

    // ---- CSR by dst (incl self loops), parallel scan ----
    hipMemsetAsync(cnt, 0, (size_t)N * 4, stream);
    count_dst<<<(EN + 255) / 256, 256, 0, stream>>>(ei, cnt, E, N);
    scan_blocks<<<NB, 256, 0, stream>>>(cnt, pref, bsums, N);
    scan_sums<<<1, 64, 0, stream>>>(bsums, NB);
    scan_apply<<<NB, 256, 0, stream>>>(pref, bsums, indptr, cursor, N, EN);
    scatter_edges<<<(EN + 255) / 256, 256, 0, stream>>>(ei, cursor, col, E, N);

    // ---- GAT layers ----
    const int Kp[5] = {48, 64, 128, 256, 128};   // padded input dims
    const int Hs[5] = {8, 16, 8, 8, 16};
    const int Cs[5] = {64, 128, 256, 128, 2};
    const int btOffA[5] = {0, 24576, 155648, 417792, 0};
    const int weOffA[5] = {0, 768, 2816, 4864, 8960};

    const __half* hin16 = hA16;
    __half* hout16[4]  = {hB16, hA16, hB16, hA16};

    for (int lyr = 0; lyr < 5; ++lyr) {
        int KP = Kp[lyr], H = Hs[lyr], C = Cs[lyr];
        int KA = H * KP;
        esed_kernel<<<(N * 2 * H + 255) / 256, 256, 0, stream>>>(hin16, wesed + weOffA[lyr],
                                                                 esed, N, KP, 2 * H);
        attn_kernel<<<(N * H + 255) / 256, 256, 0, stream>>>(esed, indptr, col,
                                                             palpha, zinv, N, H);
        if (lyr == 0)
            gat_gather<8, 48, 10><<<(N + 9) / 10, 240, 0, stream>>>(hin16, palpha, zinv, indptr, col, g, N);
        else if (lyr == 1)
            gat_gather<16, 64, 8><<<(N + 7) / 8, 256, 0, stream>>>(hin16, palpha, zinv, indptr, col, g, N);
        else if (lyr == 2)
            gat_gather<8, 128, 4><<<(N + 3) / 4, 256, 0, stream>>>(hin16, palpha, zinv, indptr, col, g, N);
        else if (lyr == 3)
            gat_gather<8, 256, 2><<<(N + 1) / 2, 256, 0, stream>>>(hin16, palpha, zinv, indptr, col, g, N);
        else
            gat_gather<16, 128, 4><<<(N + 3) / 4, 256, 0, stream>>>(hin16, palpha, zinv, indptr, col, g, N);

        if (lyr < 4) {
            const unsigned short* btL = bt + btOffA[lyr];
            int gx = (N + 63) / 64;        // 157
            gemm_lds<<<dim3(gx, C / 64), 256, 0, stream>>>(g, btL, gb[lyr], masks,
                                                           hout16[lyr], N, KA, C);
            hin16 = hout16[lyr];
        } else {
            final5_kernel<<<(N + 3) / 4, 256, 0, stream>>>(g, wstack, gb[4], masks, x,
                                                           (float*)d_out, N, KA);
        }
    }
}

// Round 5
// 549.736 us; speedup vs baseline: 1.1650x; 1.0050x over previous
//
#include <hip/hip_runtime.h>
#include <hip/hip_fp16.h>
#include <math.h>

// ---------------------------------------------------------------------------
// NetGlobGATFix. R21: wider gather loads + fused final layer.
//   - gat_gather4: half4 (8B/lane) edge gathers for KP>=64 layers (was half2
//     = 4B/lane, below the coalescing sweet spot) -> half the load insts,
//     32B in flight per thread. Same per-channel accumulation order.
//   - Layer 4: FINAL path fuses final5 into the gather epilogue (dot with W5
//     in registers + 32-lane shfl reduce) -> kills the 41MB g write + 41MB
//     re-read and one dispatch.
//   - Everything else identical to R20 (552.5us).
// ---------------------------------------------------------------------------

#define DEVFN static __device__ __forceinline__

typedef __attribute__((ext_vector_type(8))) _Float16 half8;
typedef __attribute__((ext_vector_type(4))) _Float16 half4v;
typedef __attribute__((ext_vector_type(4))) float f32x4;

DEVFN float selu_f(float v) {
    const float scale = 1.0507009873554805f;
    const float alpha = 1.6732632423543772f;
    return v > 0.f ? scale * v : scale * alpha * (expf(v) - 1.f);
}

DEVFN float lrelu02(float v) { return v > 0.f ? v : 0.2f * v; }

// ---------------- CNN (padded 66x66 layout) ----------------
#define PST 66
#define PSZ (66 * 66)

__global__ void pad_input(const float* __restrict__ cf, float* __restrict__ out) {
    int t = blockIdx.x * blockDim.x + threadIdx.x;
    if (t >= 4 * 4096) return;
    int c = t >> 12, pix = t & 4095;
    int y = pix >> 6, x = pix & 63;
    out[c * PSZ + (y + 1) * PST + (x + 1)] = cf[t];
}

template <int CIN>
__global__ __launch_bounds__(256) void conv3x3_pad(const float* __restrict__ in,
                                                   const float* __restrict__ w,
                                                   const float* __restrict__ b,
                                                   float* __restrict__ out) {
    int x  = threadIdx.x & 63;
    int yg = threadIdx.x >> 6;
    int y  = blockIdx.x * 4 + yg;          // 0..63
    int co = blockIdx.y;
    float acc = b[co];
    const float* wp = w + (size_t)co * CIN * 9;
#pragma unroll 4
    for (int ci = 0; ci < CIN; ++ci) {
        const float* ip = in + ci * PSZ + y * PST + x;
        const float* wr = wp + ci * 9;
        acc += wr[0] * ip[0]           + wr[1] * ip[1]           + wr[2] * ip[2]
             + wr[3] * ip[PST]         + wr[4] * ip[PST + 1]     + wr[5] * ip[PST + 2]
             + wr[6] * ip[2 * PST]     + wr[7] * ip[2 * PST + 1] + wr[8] * ip[2 * PST + 2];
    }
    out[(size_t)co * PSZ + (y + 1) * PST + (x + 1)] = selu_f(acc);
}

__global__ void avgpool_c(const float* __restrict__ in, float* __restrict__ gfeat) {
    int c = blockIdx.x;            // 24 blocks
    int t = threadIdx.x;           // 256 threads
    float s = 0.f;
    for (int i = t; i < 4096; i += 256) {
        int y = i >> 6, x = i & 63;
        s += in[c * PSZ + (y + 1) * PST + (x + 1)];
    }
#pragma unroll
    for (int off = 32; off >= 1; off >>= 1) s += __shfl_xor(s, off);
    __shared__ float red[4];
    int wave = t >> 6, lane = t & 63;
    if (lane == 0) red[wave] = s;
    __syncthreads();
    if (t == 0) gfeat[c] = (red[0] + red[1] + red[2] + red[3]) * (1.f / 4096.f);
}

// ---------------- node feature init (padded to 48 ch, fp16) + masks ---------
__global__ void build_h0(const float* __restrict__ x, const float* __restrict__ gfeat,
                         __half* __restrict__ h0f, unsigned* __restrict__ masks, int N) {
    int n = blockIdx.x * blockDim.x + threadIdx.x;
    if (n >= N) return;
    float x0 = x[n * 10 + 0], x1 = x[n * 10 + 1];
    unsigned mk = (x0 == 1.f ? 1u : 0u) | (x0 == 0.f ? 2u : 0u) |
                  (x1 == 0.f ? 4u : 0u) | (x1 == 1.f ? 8u : 0u);
    masks[n] = mk;
    __half* hq = h0f + (size_t)n * 48;
#pragma unroll
    for (int j = 0; j < 48; ++j) {
        float v = (j < 24) ? gfeat[j] : (j < 34 ? x[n * 10 + (j - 24)] : 0.f);
        hq[j] = __float2half(v);
    }
}

// ---------------- CSR build (parallel scan) ----------------
__global__ void count_dst(const int* __restrict__ ei, int* __restrict__ cnt, int E, int N) {
    int t = blockIdx.x * blockDim.x + threadIdx.x;
    if (t >= E + N) return;
    int dst = (t < E) ? ei[E + t] : (t - E);
    atomicAdd(&cnt[dst], 1);
}

__global__ void scan_blocks(const int* __restrict__ cnt, int* __restrict__ pref,
                            int* __restrict__ bsums, int n) {
    __shared__ int sdata[256];
    int i = blockIdx.x * 256 + threadIdx.x;
    int v = (i < n) ? cnt[i] : 0;
    sdata[threadIdx.x] = v;
    __syncthreads();
    for (int off = 1; off < 256; off <<= 1) {
        int tmp = (threadIdx.x >= off) ? sdata[threadIdx.x - off] : 0;
        __syncthreads();
        sdata[threadIdx.x] += tmp;
        __syncthreads();
    }
    if (i < n) pref[i] = sdata[threadIdx.x] - v;
    if (threadIdx.x == 255) bsums[blockIdx.x] = sdata[255];
}

__global__ void scan_sums(int* __restrict__ bsums, int nb) {
    int tid = threadIdx.x;                 // 64
    int orig = (tid < nb) ? bsums[tid] : 0;
    int v = orig;
#pragma unroll
    for (int off = 1; off < 64; off <<= 1) {
        int u = __shfl_up(v, off);
        if (tid >= off) v += u;
    }
    if (tid < nb) bsums[tid] = v - orig;
}

__global__ void scan_apply(const int* __restrict__ pref, const int* __restrict__ bsums,
                           int* __restrict__ indptr, int* __restrict__ cursor,
                           int n, int total) {
    int i = blockIdx.x * 256 + threadIdx.x;
    if (i == 0) indptr[n] = total;
    if (i >= n) return;
    int e = bsums[blockIdx.x] + pref[i];
    indptr[i] = e;
    cursor[i] = e;
}

__global__ void scatter_edges(const int* __restrict__ ei, int* __restrict__ cursor,
                              int* __restrict__ col, int E, int N) {
    int t = blockIdx.x * blockDim.x + threadIdx.x;
    if (t >= E + N) return;
    int src, dst;
    if (t < E) { src = ei[t]; dst = ei[E + t]; }
    else       { src = dst = t - E; }
    int pos = atomicAdd(&cursor[dst], 1);
    col[pos] = src;
}

// ---------------- fused one-shot weight prep --------------------------------
// bt layout per layer: bt[btOff + m*KA + h*Kp + k] = fp16(W[k*HC + h*C + m])
// wesed[weOff + k*2H + o] = sum_c W[k,h*C+c]*a[h,c]  (h=o%H, a=as/ad by o<H).
// wstack (layer 4, C=2): wstack[(h*Kp+k)*2+c] = W4[k*32 + h*2 + c].
__global__ __launch_bounds__(256) void prep_all(
        const float* __restrict__ W0, const float* __restrict__ W1,
        const float* __restrict__ W2, const float* __restrict__ W3,
        const float* __restrict__ W4,
        const float* __restrict__ as0, const float* __restrict__ as1,
        const float* __restrict__ as2, const float* __restrict__ as3,
        const float* __restrict__ as4,
        const float* __restrict__ ad0, const float* __restrict__ ad1,
        const float* __restrict__ ad2, const float* __restrict__ ad3,
        const float* __restrict__ ad4,
        unsigned short* __restrict__ bt, float* __restrict__ wesed,
        float* __restrict__ wstack) {
    const int Kc[5]  = {34, 64, 128, 256, 128};
    const int Kpc[5] = {48, 64, 128, 256, 128};
    const int Hc[5]  = {8, 16, 8, 8, 16};
    const int Cc[5]  = {64, 128, 256, 128, 2};
    const int HCc[5] = {512, 2048, 2048, 1024, 32};
    const int KAc[5] = {384, 1024, 1024, 2048, 2048};
    const int btOff[5] = {0, 24576, 155648, 417792, 679936};
    const int weOff[5] = {0, 768, 2816, 4864, 8960};

    int b = blockIdx.x, tid = threadIdx.x;

    if (b < 168) {
        // ---- LDS-tiled transpose, one (layer, head, 64x64 tile) per block --
        int lyr, tloc;
        if (b < 8)        { lyr = 0; tloc = b; }
        else if (b < 40)  { lyr = 1; tloc = b - 8; }
        else if (b < 104) { lyr = 2; tloc = b - 40; }
        else              { lyr = 3; tloc = b - 104; }
        const int ktl[4] = {1, 1, 2, 4};   // ceil(Kp/64)
        const int mtl[4] = {1, 2, 4, 2};   // ceil(C/64)
        int kt = ktl[lyr], mt = mtl[lyr];
        int per_h = kt * mt;
        int h = tloc / per_h, r = tloc - h * per_h;
        int ki = r % kt, mi = r / kt;
        int k0 = ki * 64, m0 = mi * 64;
        int K = Kc[lyr], Kp = Kpc[lyr], C = Cc[lyr], HC = HCc[lyr], KA = KAc[lyr];
        const float* W;
        if (lyr == 0) W = W0; else if (lyr == 1) W = W1;
        else if (lyr == 2) W = W2; else W = W3;

        __shared__ float tile[64][65];
        int c = tid & 63, rg = tid >> 6;
        for (int r2 = rg; r2 < 64; r2 += 4) {       // coalesced 256B reads
            int k = k0 + r2, m = m0 + c;
            float v = (k < K && m < C) ? W[(size_t)k * HC + h * C + m] : 0.f;
            tile[r2][c] = v;
        }
        __syncthreads();
        unsigned short* bp = bt + btOff[lyr];
        for (int mr = rg; mr < 64; mr += 4) {       // coalesced 128B fp16 writes
            int m = m0 + mr, k = k0 + c;
            if (m < C && k < Kp)
                bp[(size_t)m * KA + h * Kp + k] =
                    __half_as_ushort(__float2half(tile[c][mr]));
        }
    } else if (b < 184) {
        // ---- wstack for layer 4 (C=2): 4096 outputs ----
        int u = (b - 168) * 256 + tid;              // Kp=128, H=16, HC=32
        int cc = u & 1, rr = u >> 1;
        int h = rr >> 7, k = rr & 127;
        wstack[u] = W4[k * 32 + h * 2 + cc];
    } else {
        // ---- wesed dots: sizes {768,2048,2048,4096,4096} -> 51 blocks ----
        int wb = b - 184;
        int lyr, u0;
        if (wb < 3)       { lyr = 0; u0 = wb * 256; }
        else if (wb < 11) { lyr = 1; u0 = (wb - 3) * 256; }
        else if (wb < 19) { lyr = 2; u0 = (wb - 11) * 256; }
        else if (wb < 35) { lyr = 3; u0 = (wb - 19) * 256; }
        else              { lyr = 4; u0 = (wb - 35) * 256; }
        int u = u0 + tid;
        int K = Kc[lyr], Kp = Kpc[lyr], H = Hc[lyr], C = Cc[lyr], HC = HCc[lyr];
        int H2 = 2 * H;
        if (u < Kp * H2) {
            int k = u / H2, o = u - k * H2;
            float s = 0.f;
            if (k < K) {
                int h = (o < H) ? o : o - H;
                const float *W, *as_, *ad_;
                if (lyr == 0)      { W = W0; as_ = as0; ad_ = ad0; }
                else if (lyr == 1) { W = W1; as_ = as1; ad_ = ad1; }
                else if (lyr == 2) { W = W2; as_ = as2; ad_ = ad2; }
                else if (lyr == 3) { W = W3; as_ = as3; ad_ = ad3; }
                else               { W = W4; as_ = as4; ad_ = ad4; }
                const float* av = ((o < H) ? as_ : ad_) + h * C;
                const float* wp = W + (size_t)k * HC + h * C;
#pragma unroll 4
                for (int c2 = 0; c2 < C; ++c2) s += wp[c2] * av[c2];
            }
            wesed[weOff[lyr] + u] = s;
        }
    }
}

// ---------------- es/ed: esed[n, o] = hin16[n,:] @ wesed[:,o], o < 2H -------
__global__ void esed_kernel(const __half* __restrict__ hin, const float* __restrict__ wesed,
                            float* __restrict__ esed, int N, int Kp, int H2) {
    int t = blockIdx.x * blockDim.x + threadIdx.x;
    if (t >= N * H2) return;
    int n = t / H2, o = t - n * H2;
    const __half2* hp = (const __half2*)(hin + (size_t)n * Kp);
    float s = 0.f;
    for (int k2 = 0; k2 < Kp / 2; ++k2) {
        float2 f = __half22float2(hp[k2]);
        s += f.x * wesed[(2 * k2) * H2 + o] + f.y * wesed[(2 * k2 + 1) * H2 + o];
    }
    esed[t] = s;
}

// -------- attention: single pass, 4-deep gather pipeline --------------------
__global__ void attn_kernel(const float* __restrict__ esed,
                            const int* __restrict__ indptr, const int* __restrict__ col,
                            float* __restrict__ palpha, float* __restrict__ zinv,
                            int N, int H) {
    int t = blockIdx.x * blockDim.x + threadIdx.x;
    if (t >= N * H) return;
    int n = t / H, h = t - n * H;
    int H2 = 2 * H;
    float edv = esed[n * H2 + H + h];
    int beg = indptr[n], end = indptr[n + 1];
    float z = 0.f;
    int i = beg;
    for (; i + 3 < end; i += 4) {
        int s0 = col[i], s1 = col[i + 1], s2 = col[i + 2], s3 = col[i + 3];
        float e0 = esed[s0 * H2 + h];
        float e1 = esed[s1 * H2 + h];
        float e2 = esed[s2 * H2 + h];
        float e3 = esed[s3 * H2 + h];
        float p0 = expf(lrelu02(e0 + edv));
        float p1 = expf(lrelu02(e1 + edv));
        float p2 = expf(lrelu02(e2 + edv));
        float p3 = expf(lrelu02(e3 + edv));
        palpha[(size_t)(i + 0) * H + h] = p0;
        palpha[(size_t)(i + 1) * H + h] = p1;
        palpha[(size_t)(i + 2) * H + h] = p2;
        palpha[(size_t)(i + 3) * H + h] = p3;
        z += p0; z += p1; z += p2; z += p3;
    }
    for (; i < end; ++i) {
        float e = lrelu02(esed[col[i] * H2 + h] + edv);
        float p = expf(e);
        palpha[(size_t)i * H + h] = p;
        z += p;
    }
    zinv[t] = (1.f / H) / (z + 1e-16f);
}

// -------- gather (layer 0 only, KP=48): half2 loads, 4-deep ------------------
template <int H, int KP, int NPB>
__global__ __launch_bounds__(NPB * KP / 2) void gat_gather(
        const __half* __restrict__ hinf, const float* __restrict__ palpha,
        const float* __restrict__ zinv, const int* __restrict__ indptr,
        const int* __restrict__ col, __half* __restrict__ g, int N) {
    const int TPN = KP / 2;
    int sub = threadIdx.x / TPN;
    int j   = threadIdx.x % TPN;
    int n = blockIdx.x * NPB + sub;
    if (n >= N) return;
    int c0 = j * 2;
    float acc[H][2];
#pragma unroll
    for (int h = 0; h < H; ++h) { acc[h][0] = 0.f; acc[h][1] = 0.f; }
    int beg = indptr[n], end = indptr[n + 1];
    int i = beg;
    for (; i + 3 < end; i += 4) {
        int s0 = col[i], s1 = col[i + 1], s2 = col[i + 2], s3 = col[i + 3];
        __half2 hv0 = *(const __half2*)(hinf + (size_t)s0 * KP + c0);
        __half2 hv1 = *(const __half2*)(hinf + (size_t)s1 * KP + c0);
        __half2 hv2 = *(const __half2*)(hinf + (size_t)s2 * KP + c0);
        __half2 hv3 = *(const __half2*)(hinf + (size_t)s3 * KP + c0);
        float2 fv[4] = {__half22float2(hv0), __half22float2(hv1),
                        __half22float2(hv2), __half22float2(hv3)};
#pragma unroll
        for (int e = 0; e < 4; ++e) {
            const float2* ap = (const float2*)(palpha + (size_t)(i + e) * H);
            float2 f = fv[e];
#pragma unroll
            for (int h2 = 0; h2 < H / 2; ++h2) {
                float2 aa = ap[h2];
                acc[2 * h2 + 0][0] += aa.x * f.x;
                acc[2 * h2 + 0][1] += aa.x * f.y;
                acc[2 * h2 + 1][0] += aa.y * f.x;
                acc[2 * h2 + 1][1] += aa.y * f.y;
            }
        }
    }
    for (; i < end; ++i) {
        int src = col[i];
        __half2 hv = *(const __half2*)(hinf + (size_t)src * KP + c0);
        float2 f = __half22float2(hv);
        const float2* ap = (const float2*)(palpha + (size_t)i * H);
#pragma unroll
        for (int h2 = 0; h2 < H / 2; ++h2) {
            float2 aa = ap[h2];
            acc[2 * h2 + 0][0] += aa.x * f.x;
            acc[2 * h2 + 0][1] += aa.x * f.y;
            acc[2 * h2 + 1][0] += aa.y * f.x;
            acc[2 * h2 + 1][1] += aa.y * f.y;
        }
    }
    __half* gp = g + (size_t)n * (H * KP) + c0;
#pragma unroll
    for (int h = 0; h < H; ++h) {
        float zf = zinv[n * H + h];
        *(__half2*)(gp + h * KP) = __floats2half2_rn(acc[h][0] * zf, acc[h][1] * zf);
    }
}

// -------- gather: half4 (8B) loads, 4-deep; FINAL fuses the C=2 last layer --
// thread j of a node owns channels [4j, 4j+4). Same per-channel accumulation
// order as the half2 version (bit-identical sums).
template <int H, int KP, int NPB, int FINAL>
__global__ __launch_bounds__(NPB * KP / 4) void gat_gather4(
        const __half* __restrict__ hinf, const float* __restrict__ palpha,
        const float* __restrict__ zinv, const int* __restrict__ indptr,
        const int* __restrict__ col, __half* __restrict__ g,
        const float* __restrict__ W5, const float* __restrict__ b5,
        const unsigned* __restrict__ masks, const float* __restrict__ x,
        float* __restrict__ outp, int N) {
    const int TPN = KP / 4;
    int sub = threadIdx.x / TPN;
    int j   = threadIdx.x % TPN;
    int n = blockIdx.x * NPB + sub;
    if (n >= N) return;
    int c0 = j * 4;
    float acc[H][4];
#pragma unroll
    for (int h = 0; h < H; ++h)
#pragma unroll
        for (int t = 0; t < 4; ++t) acc[h][t] = 0.f;

    int beg = indptr[n], end = indptr[n + 1];
    int i = beg;
    for (; i + 3 < end; i += 4) {
        int s0 = col[i], s1 = col[i + 1], s2 = col[i + 2], s3 = col[i + 3];
        half4v hv0 = *(const half4v*)(hinf + (size_t)s0 * KP + c0);
        half4v hv1 = *(const half4v*)(hinf + (size_t)s1 * KP + c0);
        half4v hv2 = *(const half4v*)(hinf + (size_t)s2 * KP + c0);
        half4v hv3 = *(const half4v*)(hinf + (size_t)s3 * KP + c0);
#pragma unroll
        for (int e = 0; e < 4; ++e) {
            half4v hv = (e == 0) ? hv0 : (e == 1) ? hv1 : (e == 2) ? hv2 : hv3;
            float f[4] = {(float)hv[0], (float)hv[1], (float)hv[2], (float)hv[3]};
            const float2* ap = (const float2*)(palpha + (size_t)(i + e) * H);
#pragma unroll
            for (int h2 = 0; h2 < H / 2; ++h2) {
                float2 aa = ap[h2];
#pragma unroll
                for (int t = 0; t < 4; ++t) {
                    acc[2 * h2 + 0][t] += aa.x * f[t];
                    acc[2 * h2 + 1][t] += aa.y * f[t];
                }
            }
        }
    }
    for (; i < end; ++i) {
        int src = col[i];
        half4v hv = *(const half4v*)(hinf + (size_t)src * KP + c0);
        float f[4] = {(float)hv[0], (float)hv[1], (float)hv[2], (float)hv[3]};
        const float2* ap = (const float2*)(palpha + (size_t)i * H);
#pragma unroll
        for (int h2 = 0; h2 < H / 2; ++h2) {
            float2 aa = ap[h2];
#pragma unroll
            for (int t = 0; t < 4; ++t) {
                acc[2 * h2 + 0][t] += aa.x * f[t];
                acc[2 * h2 + 1][t] += aa.y * f[t];
            }
        }
    }

    if (!FINAL) {
        __half* gp = g + (size_t)n * (H * KP) + c0;
#pragma unroll
        for (int h = 0; h < H; ++h) {
            float zf = zinv[n * H + h];
            __half2 lo = __floats2half2_rn(acc[h][0] * zf, acc[h][1] * zf);
            __half2 hi = __floats2half2_rn(acc[h][2] * zf, acc[h][3] * zf);
            union { __half2 h2[2]; float2 f2; } u;
            u.h2[0] = lo; u.h2[1] = hi;
            *(float2*)(gp + h * KP) = u.f2;
        }
    } else {
        // fused last layer: a = sum_h zinv_h * (acc[h][:] . W5[h*KP+c0+:, 0/1])
        float a0 = 0.f, a1 = 0.f;
#pragma unroll
        for (int h = 0; h < H; ++h) {
            float zf = zinv[n * H + h];
            const float* wp = W5 + (size_t)(h * KP + c0) * 2;
            float4 w01 = *(const float4*)(wp);       // k=c0, c0+1
            float4 w23 = *(const float4*)(wp + 4);   // k=c0+2, c0+3
            float p0 = acc[h][0] * w01.x + acc[h][1] * w01.z +
                       acc[h][2] * w23.x + acc[h][3] * w23.z;
            float p1 = acc[h][0] * w01.y + acc[h][1] * w01.w +
                       acc[h][2] * w23.y + acc[h][3] * w23.w;
            a0 += zf * p0;
            a1 += zf * p1;
        }
        // reduce across the node's TPN(=32) threads (contiguous lanes)
#pragma unroll
        for (int off = TPN / 2; off >= 1; off >>= 1) {
            a0 += __shfl_xor(a0, off);
            a1 += __shfl_xor(a1, off);
        }
        if (j == 0) {
            unsigned mk = masks[n];
            float v0 = x[n * 10 + 0] + selu_f(a0 + b5[0]);
            float v1 = x[n * 10 + 1] + selu_f(a1 + b5[1]);
            if (mk & 2u) v0 = 0.f; else if (mk & 1u) v0 = 1.f;
            if (mk & 8u) v1 = 1.f; else if (mk & 4u) v1 = 0.f;
            outp[n * 2 + 0] = v0;
            outp[n * 2 + 1] = v1;
        }
    }
}

// ---------------- LDS-staged f16 MFMA GEMM (64x64 tile, BK=64) --------------
#define LDP 72
__global__ __launch_bounds__(256) void gemm_lds(const __half* __restrict__ A,
                                                const unsigned short* __restrict__ Bhi,
                                                const float* __restrict__ bias,
                                                const unsigned* __restrict__ masks,
                                                __half* __restrict__ O16,
                                                int N, int K, int M) {
    __shared__ __half lA[64 * LDP], lB[64 * LDP];
    int tid = threadIdx.x;
    int wave = tid >> 6, lane = tid & 63;
    int ln16 = lane & 15, q = lane >> 4;
    int row0 = blockIdx.x * 64;
    int col0 = blockIdx.y * 64;

    int r0 = tid >> 3, r1 = r0 + 32;
    int ac = (tid & 7) * 8;                      // col offset in halves
    int ga0 = min(row0 + r0, N - 1);
    int ga1 = min(row0 + r1, N - 1);
    const __half* Bp = (const __half*)Bhi;
    const __half* a0p = A + (size_t)ga0 * K + ac;
    const __half* a1p = A + (size_t)ga1 * K + ac;
    const __half* b0p = Bp + (size_t)(col0 + r0) * K + ac;
    const __half* b1p = Bp + (size_t)(col0 + r1) * K + ac;

    half8 ra0 = *(const half8*)(a0p);
    half8 ra1 = *(const half8*)(a1p);
    half8 rb0 = *(const half8*)(b0p);
    half8 rb1 = *(const half8*)(b1p);

    f32x4 acc[4];
#pragma unroll
    for (int j = 0; j < 4; ++j) acc[j] = (f32x4){0.f, 0.f, 0.f, 0.f};

    for (int kc = 0; kc < K; kc += 64) {
        __syncthreads();
        *(half8*)(lA + r0 * LDP + ac) = ra0;
        *(half8*)(lA + r1 * LDP + ac) = ra1;
        *(half8*)(lB + r0 * LDP + ac) = rb0;
        *(half8*)(lB + r1 * LDP + ac) = rb1;
        __syncthreads();
        int kn = kc + 64;
        if (kn < K) {
            ra0 = *(const half8*)(a0p + kn);
            ra1 = *(const half8*)(a1p + kn);
            rb0 = *(const half8*)(b0p + kn);
            rb1 = *(const half8*)(b1p + kn);
        }
#pragma unroll
        for (int kk = 0; kk < 2; ++kk) {
            half8 af = *(const half8*)(lA + (wave * 16 + ln16) * LDP + kk * 32 + q * 8);
#pragma unroll
            for (int j = 0; j < 4; ++j) {
                half8 bf = *(const half8*)(lB + (j * 16 + ln16) * LDP + kk * 32 + q * 8);
                acc[j] = __builtin_amdgcn_mfma_f32_16x16x32_f16(af, bf, acc[j], 0, 0, 0);
            }
        }
    }

#pragma unroll
    for (int j = 0; j < 4; ++j) {
        int cc = col0 + j * 16 + ln16;
        float bv = bias[cc];
#pragma unroll
        for (int r = 0; r < 4; ++r) {
            int rr = row0 + wave * 16 + q * 4 + r;
            if (rr >= N) continue;
            float v = selu_f(acc[j][r] + bv);
            if (cc < 2) {
                unsigned mk = masks[rr];
                if (cc == 0) { if (mk & 2u) v = 0.f; else if (mk & 1u) v = 1.f; }
                else         { if (mk & 8u) v = 1.f; else if (mk & 4u) v = 0.f; }
            }
            O16[(size_t)rr * M + cc] = __float2half(v);
        }
    }
}

// ---------------------------------------------------------------------------
extern "C" void kernel_launch(void* const* d_in, const int* in_sizes, int n_in,
                              void* d_out, int out_size, void* d_ws, size_t ws_size,
                              hipStream_t stream) {
    const float* x   = (const float*)d_in[0];
    const int*   ei  = (const int*)d_in[1];
    const float* cf  = (const float*)d_in[2];
    const float* cw[4] = {(const float*)d_in[3], (const float*)d_in[5],
                          (const float*)d_in[7], (const float*)d_in[9]};
    const float* cb[4] = {(const float*)d_in[4], (const float*)d_in[6],
                          (const float*)d_in[8], (const float*)d_in[10]};
    const float* gw[5], *gas[5], *gad[5], *gb[5];
    for (int i = 0; i < 5; ++i) {
        gw[i]  = (const float*)d_in[11 + 4 * i];
        gas[i] = (const float*)d_in[12 + 4 * i];
        gad[i] = (const float*)d_in[13 + 4 * i];
        gb[i]  = (const float*)d_in[14 + 4 * i];
    }
    const int N = in_sizes[0] / 10;        // 10000
    const int E = in_sizes[1] / 2;         // 160000
    const int EN = E + N;
    const int NB = (N + 255) / 256;        // scan blocks (40)

    // ---- workspace carve-up ----
    char* base = (char*)d_ws;
    size_t off = 0;
    auto alloc = [&](size_t bytes) -> char* {
        char* p = base + off;
        off = (off + bytes + 255) & ~(size_t)255;
        return p;
    };
    float* cfp   = (float*)alloc((size_t)4 * PSZ * 4);
    float* c1p   = (float*)alloc((size_t)16 * PSZ * 4);
    float* c2p   = (float*)alloc((size_t)32 * PSZ * 4);
    float* c3p   = (float*)alloc((size_t)64 * PSZ * 4);
    float* c4p   = (float*)alloc((size_t)24 * PSZ * 4);
    float* gfeat = (float*)alloc(24 * 4);
    __half* hA16 = (__half*)alloc((size_t)N * 256 * 2);
    __half* hB16 = (__half*)alloc((size_t)N * 256 * 2);
    __half* g    = (__half*)alloc((size_t)N * 2048 * 2);
    float* esed  = (float*)alloc((size_t)N * 32 * 4);
    float* zinv  = (float*)alloc((size_t)N * 16 * 4);
    float* palpha = (float*)alloc((size_t)EN * 16 * 4);      // fp32 numerators
    float* wesed = (float*)alloc((size_t)13056 * 4);         // all 5 layers
    float* wstack= (float*)alloc((size_t)2048 * 2 * 4);
    unsigned short* bt = (unsigned short*)alloc((size_t)679936 * 2);  // 4 GEMM layers
    unsigned* masks = (unsigned*)alloc((size_t)N * 4);
    int* cnt    = (int*)alloc((size_t)N * 4);
    int* pref   = (int*)alloc((size_t)N * 4);
    int* bsums  = (int*)alloc(64 * 4);
    int* indptr = (int*)alloc((size_t)(N + 1) * 4);
    int* cursor = (int*)alloc((size_t)N * 4);
    int* col    = (int*)alloc((size_t)EN * 4);
    (void)ws_size; // ~78 MB

    // ---- one-shot fused weight prep (all 5 layers) ----
    prep_all<<<235, 256, 0, stream>>>(gw[0], gw[1], gw[2], gw[3], gw[4],
                                      gas[0], gas[1], gas[2], gas[3], gas[4],
                                      gad[0], gad[1], gad[2], gad[3], gad[4],
                                      bt, wesed, wstack);

    // ---- CNN (padded layout; single memset zeroes all borders) ----
    hipMemsetAsync(cfp, 0, (size_t)140 * PSZ * 4, stream);
    pad_input<<<(4 * 4096 + 255) / 256, 256, 0, stream>>>(cf, cfp);
    conv3x3_pad<4><<<dim3(16, 16), 256, 0, stream>>>(cfp, cw[0], cb[0], c1p);
    conv3x3_pad<16><<<dim3(16, 32), 256, 0, stream>>>(c1p, cw[1], cb[1], c2p);
    conv3x3_pad<32><<<dim3(16, 64), 256, 0, stream>>>(c2p, cw[2], cb[2], c3p);
    conv3x3_pad<64><<<dim3(16, 24), 256, 0, stream>>>(c3p, cw[3], cb[3], c4p);
    avgpool_c<<<24, 256, 0, stream>>>(c4p, gfeat);

    // ---- h0 (padded to 48, fp16) + masks ----
    build_h0<<<(N + 255) / 256, 256, 0, stream>>>(x, gfeat, hA16, masks, N);

    // ---- CSR by dst (incl self loops), parallel scan ----
    hipMemsetAsync(cnt, 0, (size_t)N * 4, stream);
    count_dst<<<(EN + 255) / 256, 256, 0, stream>>>(ei, cnt, E, N);
    scan_blocks<<<NB, 256, 0, stream>>>(cnt, pref, bsums, N);
    scan_sums<<<1, 64, 0, stream>>>(bsums, NB);
    scan_apply<<<NB, 256, 0, stream>>>(pref, bsums, indptr, cursor, N, EN);
    scatter_edges<<<(EN + 255) / 256, 256, 0, stream>>>(ei, cursor, col, E, N);

    // ---- GAT layers ----
    const int Hs[5] = {8, 16, 8, 8, 16};
    const int Cs[5] = {64, 128, 256, 128, 2};
    const int Kp[5] = {48, 64, 128, 256, 128};
    const int btOffA[5] = {0, 24576, 155648, 417792, 0};
    const int weOffA[5] = {0, 768, 2816, 4864, 8960};

    const __half* hin16 = hA16;
    __half* hout16[4]  = {hB16, hA16, hB16, hA16};

    for (int lyr = 0; lyr < 5; ++lyr) {
        int KP = Kp[lyr], H = Hs[lyr], C = Cs[lyr];
        int KA = H * KP;
        esed_kernel<<<(N * 2 * H + 255) / 256, 256, 0, stream>>>(hin16, wesed + weOffA[lyr],
                                                                 esed, N, KP, 2 * H);
        attn_kernel<<<(N * H + 255) / 256, 256, 0, stream>>>(esed, indptr, col,
                                                             palpha, zinv, N, H);
        if (lyr == 0)
            gat_gather<8, 48, 10><<<(N + 9) / 10, 240, 0, stream>>>(
                hin16, palpha, zinv, indptr, col, g, N);
        else if (lyr == 1)
            gat_gather4<16, 64, 16, 0><<<(N + 15) / 16, 256, 0, stream>>>(
                hin16, palpha, zinv, indptr, col, g,
                nullptr, nullptr, nullptr, nullptr, nullptr, N);
        else if (lyr == 2)
            gat_gather4<8, 128, 8, 0><<<(N + 7) / 8, 256, 0, stream>>>(
                hin16, palpha, zinv, indptr, col, g,
                nullptr, nullptr, nullptr, nullptr, nullptr, N);
        else if (lyr == 3)
            gat_gather4<8, 256, 4, 0><<<(N + 3) / 4, 256, 0, stream>>>(
                hin16, palpha, zinv, indptr, col, g,
                nullptr, nullptr, nullptr, nullptr, nullptr, N);
        else
            gat_gather4<16, 128, 8, 1><<<(N + 7) / 8, 256, 0, stream>>>(
                hin16, palpha, zinv, indptr, col, nullptr,
                wstack, gb[4], masks, x, (float*)d_out, N);

        if (lyr < 4) {
            const unsigned short* btL = bt + btOffA[lyr];
            int gx = (N + 63) / 64;        // 157
            gemm_lds<<<dim3(gx, C / 64), 256, 0, stream>>>(g, btL, gb[lyr], masks,
                                                           hout16[lyr], N, KA, C);
            hin16 = hout16[lyr];
        }
    }
}